// Round 8
// baseline (1599.312 us; speedup 1.0000x reference)
//
#include <hip/hip_runtime.h>

#define DEV __device__ __forceinline__

typedef unsigned short u16;
typedef unsigned int   u32;
typedef unsigned long long u64;
typedef float f32x4 __attribute__((ext_vector_type(4)));
typedef __bf16 bf16x8 __attribute__((ext_vector_type(8)));

static constexpr float BNS = 0.9999950000374997f; // 1/sqrt(1+1e-5)

DEV float b2f(u32 s){ union{u32 i; float f;} c; c.i = s<<16; return c.f; }
DEV u16   f2b(float x){ union{float f; u32 i;} c; c.f=x; u32 r=c.i + 0x7fffu + ((c.i>>16)&1u); return (u16)(r>>16); }
DEV float leaky(float x){ return x>0.f ? x : 0.2f*x; }
DEV float wredsum(float v){
  #pragma unroll
  for(int d=32; d; d>>=1) v += __shfl_xor(v, d);
  return v;
}
DEV void gl16(const void* g, void* l){
  __builtin_amdgcn_global_load_lds((const __attribute__((address_space(1))) u32*)g,
                                   (__attribute__((address_space(3))) u32*)l, 16, 0, 0);
}
DEV u64 shflx64(u64 v, int m){
  u32 lo=(u32)v, hi=(u32)(v>>32);
  lo=__shfl_xor(lo,m); hi=__shfl_xor(hi,m);
  return ((u64)hi<<32)|lo;
}
DEV u64 shfl64(u64 v, int src){
  u32 lo=(u32)v, hi=(u32)(v>>32);
  lo=__shfl(lo,src); hi=__shfl(hi,src);
  return ((u64)hi<<32)|lo;
}
// full bitonic sort, descending, 64 lanes
DEV u64 bsort64(u64 k, int lane){
  #pragma unroll
  for(int kk=2; kk<=64; kk<<=1){
    #pragma unroll
    for(int j=kk>>1; j>0; j>>=1){
      u64 o = shflx64(k, j);
      bool km = ((lane & kk)==0) == ((lane & j)==0);
      k = (km == (k > o)) ? k : o;
    }
  }
  return k;
}

// ---------- prep: (B,3,N) f32 -> (B,N,4) f32 (pad 0) ----------
__global__ __launch_bounds__(256) void k_prep(const float* __restrict__ x, float* __restrict__ X0){
  int i = blockIdx.x*256 + threadIdx.x;          // b*N+n, 32768
  int b = i>>11, n = i&2047;
  const float* xb = x + ((size_t)b*3)*2048 + n;
  f32x4 v; v.x=xb[0]; v.y=xb[2048]; v.z=xb[4096]; v.w=0.f;
  ((f32x4*)X0)[i] = v;
}

// ---------- pack W1 (64,6) f32 -> (64,32) f32 matching padded H1 layout ----------
__global__ __launch_bounds__(256) void k_packw1(const float* __restrict__ W1, float* __restrict__ Wp){
  for(int u=threadIdx.x; u<2048; u+=256){
    int o=u>>5, c=u&31;
    float val=0.f;
    if(c<3)            val = W1[o*6+c];
    else if(c>=4&&c<7) val = W1[o*6+3+(c-4)];
    Wp[u]=val;
  }
}

// ---------- pack f32 weight -> bf16 ----------
__global__ __launch_bounds__(256) void k_w2b(const float* __restrict__ W, u16* __restrict__ Wb, int n){
  int i = blockIdx.x*256 + threadIdx.x;
  if(i<n) Wb[i]=f2b(W[i]);
}

// ---------- squared norms ----------
template<int CP>
__global__ __launch_bounds__(256) void k_sqnorm(const float* __restrict__ X, float* __restrict__ xx){
  int i = blockIdx.x*256 + threadIdx.x;
  const f32x4* p = (const f32x4*)(X + (size_t)i*CP);
  f32x4 a4 = {0.f,0.f,0.f,0.f};
  #pragma unroll
  for(int c=0;c<CP/4;c++){ f32x4 v=p[c]; a4 += v*v; }
  xx[i] = (a4.x+a4.y)+(a4.z+a4.w);
}

// ---------- split-bf16 pack: X (B,N,CP f32) -> XP (B,N,2CP bf16) = [h(CP), l(CP)] ----------
template<int CP>
__global__ __launch_bounds__(256) void k_split(const float* __restrict__ X, u16* __restrict__ XP){
  const int gi = blockIdx.x*256 + threadIdx.x;   // 4 threads per point
  const int i = gi>>2, part = gi&3;
  constexpr int CH = CP/4;
  const float* xr = X + (size_t)i*CP + part*CH;
  u16* ph = XP + (size_t)i*(2*CP) + part*CH;
  u16* pl = ph + CP;
  #pragma unroll
  for(int c=0;c<CH;c+=4){
    f32x4 v = *(const f32x4*)(xr+c);
    u16 h0=f2b(v.x),h1=f2b(v.y),h2=f2b(v.z),h3=f2b(v.w);
    ushort4 hh={h0,h1,h2,h3};
    ushort4 ll={f2b(v.x-b2f(h0)),f2b(v.y-b2f(h1)),f2b(v.z-b2f(h2)),f2b(v.w-b2f(h3))};
    *(ushort4*)(ph+c)=hh; *(ushort4*)(pl+c)=ll;
  }
}

// ---------- layer-1 split: X0 (B,N,4) -> XA1=[h,l,h,0..] XB1=[h,h,l,0..] (32 wide) ----------
__global__ __launch_bounds__(256) void k_split1(const float* __restrict__ X0, u16* __restrict__ XA1,
                                                u16* __restrict__ XB1){
  const int i = blockIdx.x*256 + threadIdx.x;
  f32x4 v = ((const f32x4*)X0)[i];
  u16 h0=f2b(v.x),h1=f2b(v.y),h2=f2b(v.z),h3=f2b(v.w);
  ushort4 hh={h0,h1,h2,h3};
  ushort4 ll={f2b(v.x-b2f(h0)),f2b(v.y-b2f(h1)),f2b(v.z-b2f(h2)),f2b(v.w-b2f(h3))};
  ushort4 zz={0,0,0,0};
  u16* a = XA1 + (size_t)i*32;
  u16* b = XB1 + (size_t)i*32;
  *(ushort4*)(a)=hh;  *(ushort4*)(a+4)=ll; *(ushort4*)(a+8)=hh;
  *(ushort4*)(b)=hh;  *(ushort4*)(b+4)=hh; *(ushort4*)(b+8)=ll;
  #pragma unroll
  for(int c=12;c<32;c+=4){ *(ushort4*)(a+c)=zz; *(ushort4*)(b+c)=zz; }
}

// ---------- pd GEMM over a 4-batch group: S(4,2048,2048) f32 ----------
template<int KP,int CPM,int STR>
__global__ __launch_bounds__(256) void k_pdg(const u16* __restrict__ Ab, const u16* __restrict__ Bb,
                                             float* __restrict__ Sb){
  __shared__ __align__(16) u16 As[128*32];
  __shared__ __align__(16) u16 Bs[128*32];
  const int tid=threadIdx.x, b=blockIdx.z;       // local batch 0..3
  const int n0=blockIdx.x<<7;                    // query tile base
  const int o0=blockIdx.y<<7;                    // candidate tile base
  const int wid=tid>>6, lane=tid&63, wr=wid>>1, wc=wid&1, lm=lane&15, quad=lane>>4;
  f32x4 acc[4][4];
  #pragma unroll
  for(int a=0;a<4;a++)
    #pragma unroll
    for(int c=0;c<4;c++) acc[a][c]=(f32x4){0.f,0.f,0.f,0.f};
  const int r0=tid>>2, kc=(tid&3)<<3;
  const u16* A0 = Ab + ((size_t)b*2048 + o0 + r0)*STR + kc;
  const u16* A1 = A0 + (size_t)64*STR;
  const u16* B0 = Bb + ((size_t)b*2048 + n0 + r0)*STR + kc;
  const u16* B1 = B0 + (size_t)64*STR;
  u16* Aw = As + wid*512;
  u16* Bw = Bs + wid*512;
  #pragma unroll
  for(int kk=0;kk<KP/32;kk++){
    const int k0=kk*32;
    const int aoff = (k0<CPM)? k0 : k0-CPM;        // [h,h,l]
    const int boff = (k0<2*CPM)? k0 : k0-2*CPM;    // [h,l,h]
    __syncthreads();
    gl16(A0+aoff, Aw);  gl16(A1+aoff, Aw+2048);
    gl16(B0+boff, Bw);  gl16(B1+boff, Bw+2048);
    __syncthreads();
    bf16x8 af[4], bfr[4];
    #pragma unroll
    for(int mi=0;mi<4;mi++) af[mi]=*(const bf16x8*)(As + ((wr<<6)+(mi<<4)+lm)*32 + (quad<<3));
    #pragma unroll
    for(int ni=0;ni<4;ni++) bfr[ni]=*(const bf16x8*)(Bs + ((wc<<6)+(ni<<4)+lm)*32 + (quad<<3));
    #pragma unroll
    for(int mi=0;mi<4;mi++)
      #pragma unroll
      for(int ni=0;ni<4;ni++)
        acc[mi][ni]=__builtin_amdgcn_mfma_f32_16x16x32_bf16(af[mi],bfr[ni],acc[mi][ni],0,0,0);
  }
  #pragma unroll
  for(int mi=0;mi<4;mi++){
    const int oc = o0 + (wr<<6)+(mi<<4)+(quad<<2);
    #pragma unroll
    for(int ni=0;ni<4;ni++){
      const int q = n0 + (wc<<6)+(ni<<4)+lm;
      *(f32x4*)(Sb + ((size_t)b*2048 + q)*2048 + oc) = acc[mi][ni];
    }
  }
}

// ---------- full-row wave-coop top-20 select over a 4-batch group ----------
__global__ __launch_bounds__(256) void k_selG(const float* __restrict__ Sb, const float* __restrict__ xxp,
                                              int* __restrict__ knn){
  __shared__ u64 buf[4][320];
  __shared__ u32 cw[4];
  const int w=threadIdx.x>>6, lane=threadIdx.x&63;
  const int row = blockIdx.x*4 + w;      // 0..8191 (4 batches x 2048)
  const int q = row & 2047;
  if(lane==0) cw[w]=0;
  __builtin_amdgcn_wave_barrier();
  __asm__ volatile("s_waitcnt lgkmcnt(0)" ::: "memory");
  u64 top=0, T=0; float Tf=-3.4e38f;
  auto flush=[&](){
    __builtin_amdgcn_wave_barrier();
    __asm__ volatile("s_waitcnt lgkmcnt(0)" ::: "memory");
    const int cnt=(int)cw[w];
    __builtin_amdgcn_wave_barrier();
    for(int done=0; done<cnt; done+=64){
      u64 bk = (lane < cnt-done) ? buf[w][done+lane] : 0;
      u64 sb = bsort64(bk, lane);
      u64 rev = shfl64(sb,(31-lane)&63);
      u64 c2 = (lane<32) ? (top>rev?top:rev) : 0;
      #pragma unroll
      for(int j=16;j>0;j>>=1){
        u64 o = shflx64(c2,j);
        bool km=(lane&j)==0;
        c2 = (km==(c2>o))?c2:o;
      }
      top = (lane<20)?c2:0;
    }
    T = shfl64(top,19);
    u32 Thi=(u32)(T>>32);
    u32 um = (Thi&0x80000000u)?(Thi^0x80000000u):(~Thi);
    Tf = __uint_as_float(um);
    if(lane==0) cw[w]=0;
    __builtin_amdgcn_wave_barrier();
    __asm__ volatile("s_waitcnt lgkmcnt(0)" ::: "memory");
  };
  const float* Srow = Sb + (size_t)row*2048;
  const float* xxr  = xxp + ((size_t)(row>>11)<<11);
  #pragma unroll 1
  for(int g=0;g<8;++g){
    const int c0=g*256 + (lane<<2);
    f32x4 s4=*(const f32x4*)(Srow+c0);
    f32x4 x4=*(const f32x4*)(xxr+c0);
    f32x4 p4=s4+s4-x4;
    int np=(p4.x>=Tf)+(p4.y>=Tf)+(p4.z>=Tf)+(p4.w>=Tf);
    if(__ballot(np!=0)){
      #pragma unroll
      for(int e=0;e<4;e++){
        const int col=c0+e;
        u32 u=__float_as_uint(p4[e]);
        u32 mk=u^(u32)(((int)u>>31)|0x80000000u);
        u64 key=((u64)mk<<32)|(u32)(2047-col);
        if(key>T && col!=q){
          u32 pos=atomicAdd(&cw[w],1u);
          buf[w][pos]=key;
        }
      }
      __builtin_amdgcn_wave_barrier();
      __asm__ volatile("s_waitcnt lgkmcnt(0)" ::: "memory");
      const int c=(int)cw[w];
      if(c>64) flush();
    }
  }
  flush();
  if(lane<20) knn[(size_t)row*20+lane]=2047-(int)(top&0xFFFFFFFFull);
}

// ---------- attention (channel-split, TPP threads/point) ----------
template<int CP,int HS,int TPP>
__global__ __launch_bounds__(256) void k_attn(const float* __restrict__ X, const int* __restrict__ knn,
                                              u16* __restrict__ H){
  constexpr int CH = CP/TPP;
  const int gi = blockIdx.x*256 + threadIdx.x;
  const int i = gi/TPP, t = gi%TPP;
  const float* Xb = X + (((size_t)(i>>11))<<11)*CP;
  const float* q  = X + (size_t)i*CP + t*CH;
  int nb[20];
  { const int* kp = knn + (size_t)i*20;
    #pragma unroll
    for(int j=0;j<20;j++) nb[j]=kp[j]; }
  float qc[CH];
  if constexpr(CH>=4){
    #pragma unroll
    for(int c=0;c<CH;c+=4){
      f32x4 vv = *(const f32x4*)(q+c);
      qc[c]=vv.x; qc[c+1]=vv.y; qc[c+2]=vv.z; qc[c+3]=vv.w;
    }
  } else {
    qc[0]=q[0];
  }
  float s[20];
  #pragma unroll
  for(int j=0;j<20;j++){
    const float* kr = Xb + (size_t)nb[j]*CP + t*CH;
    float a=0.f;
    if constexpr(CH>=4){
      #pragma unroll
      for(int c=0;c<CH;c+=4){
        f32x4 kv = *(const f32x4*)(kr+c);
        a += kv.x*qc[c] + kv.y*qc[c+1] + kv.z*qc[c+2] + kv.w*qc[c+3];
      }
    } else {
      a = qc[0]*kr[0];
    }
    s[j]=a;
  }
  #pragma unroll
  for(int j=0;j<20;j++){
    #pragma unroll
    for(int d=1;d<TPP;d<<=1) s[j] += __shfl_xor(s[j], d);
  }
  float mx=s[0];
  #pragma unroll
  for(int j=1;j<20;j++) mx=fmaxf(mx,s[j]);
  float sum=0.f;
  #pragma unroll
  for(int j=0;j<20;j++){ s[j]=__expf(s[j]-mx); sum+=s[j]; }
  float inv=1.f/sum;
  #pragma unroll
  for(int j=0;j<20;j++) s[j]*=inv;
  float f[CH];
  #pragma unroll
  for(int c=0;c<CH;c++) f[c]=0.f;
  #pragma unroll
  for(int j=0;j<20;j++){
    const float* kr = Xb + (size_t)nb[j]*CP + t*CH;
    const float w = s[j];
    if constexpr(CH>=4){
      #pragma unroll
      for(int c=0;c<CH;c+=4){
        f32x4 kv = *(const f32x4*)(kr+c);
        f[c]+=w*kv.x; f[c+1]+=w*kv.y; f[c+2]+=w*kv.z; f[c+3]+=w*kv.w;
      }
    } else {
      f[0]+=w*kr[0];
    }
  }
  u16* ho = H + (size_t)i*HS;
  if constexpr(CH>=4){
    #pragma unroll
    for(int c=0;c<CH;c+=4){
      ushort4 qs = {f2b(qc[c]),f2b(qc[c+1]),f2b(qc[c+2]),f2b(qc[c+3])};
      *(ushort4*)(ho + t*CH + c) = qs;
      ushort4 fs = {f2b(f[c]-qc[c]),f2b(f[c+1]-qc[c+1]),f2b(f[c+2]-qc[c+2]),f2b(f[c+3]-qc[c+3])};
      *(ushort4*)(ho + CP + t*CH + c) = fs;
    }
  } else {
    ho[t]      = f2b(qc[0]);
    ho[CP+t]   = f2b(f[0]-qc[0]);
  }
  if constexpr(HS > 2*CP){
    ushort4 zz={0,0,0,0};
    *(ushort4*)(ho + 2*CP + t*4) = zz;
    if(t < (HS-2*CP-4*TPP)/4) *(ushort4*)(ho + 2*CP + 4*TPP + t*4) = zz;
  }
}

// ---------- vector conv (O=64) ----------
template<int K>
__global__ __launch_bounds__(256) void k_vconv(const u16* __restrict__ H, const float* __restrict__ Wg,
                                               const float* __restrict__ g, const float* __restrict__ bb,
                                               float* __restrict__ Xout, u16* __restrict__ Hc, int hoff){
  __shared__ __align__(16) float Ws[K*64];   // [k][o]
  for(int u=threadIdx.x; u<K*64; u+=256){
    int o=u&63, kk=u>>6;
    Ws[u]=Wg[o*K+kk];
  }
  __syncthreads();
  const int gi = blockIdx.x*256 + threadIdx.x;
  const int i = gi>>2, oc = gi&3;
  const u16* hr = H + (size_t)i*K;
  float acc[16];
  #pragma unroll
  for(int o=0;o<16;o++) acc[o]=0.f;
  for(int k0=0;k0<K;k0+=8){
    uint4 hv = *(const uint4*)(hr+k0);
    float hh[8];
    hh[0]=b2f(hv.x&0xffff); hh[1]=b2f(hv.x>>16);
    hh[2]=b2f(hv.y&0xffff); hh[3]=b2f(hv.y>>16);
    hh[4]=b2f(hv.z&0xffff); hh[5]=b2f(hv.z>>16);
    hh[6]=b2f(hv.w&0xffff); hh[7]=b2f(hv.w>>16);
    #pragma unroll
    for(int kk=0;kk<8;kk++){
      const f32x4* wr = (const f32x4*)(Ws + (k0+kk)*64 + oc*16);
      #pragma unroll
      for(int o4=0;o4<4;o4++){
        f32x4 w = wr[o4];
        acc[o4*4]  +=hh[kk]*w.x; acc[o4*4+1]+=hh[kk]*w.y;
        acc[o4*4+2]+=hh[kk]*w.z; acc[o4*4+3]+=hh[kk]*w.w;
      }
    }
  }
  const int ob = oc*16;
  #pragma unroll
  for(int o=0;o<16;o++) acc[o]=leaky(acc[o]*(BNS*g[ob+o])+bb[ob+o]);
  float* xo = Xout + (size_t)i*64 + ob;
  #pragma unroll
  for(int o=0;o<16;o+=4){ f32x4 sv={acc[o],acc[o+1],acc[o+2],acc[o+3]}; *(f32x4*)(xo+o)=sv; }
  u16* hc = Hc + (size_t)i*512 + hoff + ob;
  #pragma unroll
  for(int o=0;o<16;o+=4){ ushort4 st={f2b(acc[o]),f2b(acc[o+1]),f2b(acc[o+2]),f2b(acc[o+3])}; *(ushort4*)(hc+o)=st; }
}

// ---------- MFMA conv ----------
template<int K,int OSTR,bool OUT32,int HCS>
__global__ __launch_bounds__(256) void k_cmfma(const u16* __restrict__ Wg, const u16* __restrict__ Hin,
                                               const float* __restrict__ g, const float* __restrict__ bb,
                                               float* __restrict__ Xout, u16* __restrict__ Hc, int hoff){
  __shared__ __align__(16) u16 As[128*32];
  __shared__ __align__(16) u16 Bs[128*32];
  const int tid=threadIdx.x, b=blockIdx.z;
  const int n0=blockIdx.x<<7, o0=blockIdx.y<<7;
  const int wid=tid>>6, lane=tid&63, wr=wid>>1, wc=wid&1, lm=lane&15, quad=lane>>4;
  f32x4 acc[4][4];
  #pragma unroll
  for(int a=0;a<4;a++)
    #pragma unroll
    for(int c=0;c<4;c++) acc[a][c]=(f32x4){0.f,0.f,0.f,0.f};
  const int r0=tid>>2, kc=(tid&3)<<3;
  const u16* A0 = Wg + (size_t)(o0+r0)*K + kc;
  const u16* A1 = A0 + (size_t)64*K;
  const u16* B0 = Hin + ((size_t)b*2048 + n0 + r0)*K + kc;
  const u16* B1 = B0 + (size_t)64*K;
  u16* Aw = As + wid*512;   // wave-uniform LDS base; HW adds lane*16B
  u16* Bw = Bs + wid*512;
  for(int k0=0;k0<K;k0+=32){
    __syncthreads();
    gl16(A0+k0, Aw);  gl16(A1+k0, Aw+2048);
    gl16(B0+k0, Bw);  gl16(B1+k0, Bw+2048);
    __syncthreads();
    bf16x8 af[4], bfr[4];
    #pragma unroll
    for(int mi=0;mi<4;mi++) af[mi]=*(const bf16x8*)(As + ((wr<<6)+(mi<<4)+lm)*32 + (quad<<3));
    #pragma unroll
    for(int ni=0;ni<4;ni++) bfr[ni]=*(const bf16x8*)(Bs + ((wc<<6)+(ni<<4)+lm)*32 + (quad<<3));
    #pragma unroll
    for(int mi=0;mi<4;mi++)
      #pragma unroll
      for(int ni=0;ni<4;ni++)
        acc[mi][ni]=__builtin_amdgcn_mfma_f32_16x16x32_bf16(af[mi],bfr[ni],acc[mi][ni],0,0,0);
  }
  #pragma unroll
  for(int mi=0;mi<4;mi++){
    const int o = o0 + (wr<<6) + (mi<<4) + (quad<<2);
    float g0=BNS*g[o],  g1v=BNS*g[o+1], g2v=BNS*g[o+2], g3v=BNS*g[o+3];
    float b0=bb[o], b1v=bb[o+1], b2v=bb[o+2], b3v=bb[o+3];
    #pragma unroll
    for(int ni=0;ni<4;ni++){
      const int n = n0 + (wc<<6) + (ni<<4) + lm;
      const size_t pt = (size_t)b*2048 + n;
      f32x4 cc = acc[mi][ni];
      float y0=leaky(cc.x*g0+b0);
      float y1=leaky(cc.y*g1v+b1v);
      float y2=leaky(cc.z*g2v+b2v);
      float y3=leaky(cc.w*g3v+b3v);
      if constexpr(OUT32){
        f32x4 sv={y0,y1,y2,y3};
        *(f32x4*)(Xout + pt*OSTR + o)=sv;
      }
      ushort4 st={f2b(y0),f2b(y1),f2b(y2),f2b(y3)};
      *(ushort4*)(Hc + pt*HCS + hoff + o)=st;
    }
  }
}

// ---------- head: per-point scores = leaky(x5 . Watt^T) ----------
__global__ __launch_bounds__(256) void k_scores(const u16* __restrict__ X5, const float* __restrict__ Watt,
                                                float* __restrict__ S){
  __shared__ __align__(16) f32x4 Wa[1024];
  for(int u=threadIdx.x; u<1024; u+=256){
    f32x4 w; w.x=Watt[u]; w.y=Watt[1024+u]; w.z=Watt[2048+u]; w.w=Watt[3072+u];
    Wa[u]=w;
  }
  __syncthreads();
  const int i = blockIdx.x*256 + threadIdx.x;
  const u16* xr = X5 + (size_t)i*1024;
  f32x4 a={0.f,0.f,0.f,0.f};
  for(int k0=0;k0<1024;k0+=8){
    uint4 hv=*(const uint4*)(xr+k0);
    float hh[8];
    hh[0]=b2f(hv.x&0xffff); hh[1]=b2f(hv.x>>16);
    hh[2]=b2f(hv.y&0xffff); hh[3]=b2f(hv.y>>16);
    hh[4]=b2f(hv.z&0xffff); hh[5]=b2f(hv.z>>16);
    hh[6]=b2f(hv.w&0xffff); hh[7]=b2f(hv.w>>16);
    #pragma unroll
    for(int kk=0;kk<8;kk++){
      f32x4 w=Wa[k0+kk];
      a.x+=hh[kk]*w.x; a.y+=hh[kk]*w.y; a.z+=hh[kk]*w.z; a.w+=hh[kk]*w.w;
    }
  }
  f32x4 sv={leaky(a.x),leaky(a.y),leaky(a.z),leaky(a.w)};
  ((f32x4*)S)[i]=sv;
}

// ---------- head: att[b,h,e] = sum_n x5[b,n,e]*S[b,n,h] (atomic partials) ----------
__global__ __launch_bounds__(256) void k_att(const u16* __restrict__ X5, const float* __restrict__ S,
                                             float* __restrict__ att){
  __shared__ __align__(16) f32x4 Sh[256];
  const int b=blockIdx.z, e=(blockIdx.x<<8)+threadIdx.x, nbase=blockIdx.y<<8;
  Sh[threadIdx.x]=((const f32x4*)S)[(((size_t)b)<<11)+nbase+threadIdx.x];
  __syncthreads();
  f32x4 a={0.f,0.f,0.f,0.f};
  const u16* xp = X5 + ((((size_t)b)<<11)+nbase)*1024 + e;
  for(int nn=0;nn<256;nn++){
    float xv=b2f(xp[(size_t)nn*1024]);
    f32x4 s=Sh[nn];
    a.x+=xv*s.x; a.y+=xv*s.y; a.z+=xv*s.z; a.w+=xv*s.w;
  }
  float* ab = att + (((size_t)b)<<12) + e;
  atomicAdd(ab,      a.x); atomicAdd(ab+1024, a.y);
  atomicAdd(ab+2048, a.z); atomicAdd(ab+3072, a.w);
}

// ---------- head: layernorm + leaky ----------
__global__ __launch_bounds__(256) void k_ln(const float* __restrict__ att, const float* __restrict__ lg,
                                            const float* __restrict__ lb, float* __restrict__ L){
  const int b=blockIdx.x, t=threadIdx.x;
  const float* a = att + (((size_t)b)<<12);
  float s=0.f, sq=0.f;
  for(int u=t;u<4096;u+=256){ float x=a[u]; s+=x; sq+=x*x; }
  s=wredsum(s); sq=wredsum(sq);
  __shared__ float rs[4], rq[4];
  const int wid=t>>6, lane=t&63;
  if(lane==0){ rs[wid]=s; rq[wid]=sq; }
  __syncthreads();
  s=rs[0]+rs[1]+rs[2]+rs[3];
  sq=rq[0]+rq[1]+rq[2]+rq[3];
  const float mean=s*(1.f/4096.f);
  const float var=sq*(1.f/4096.f)-mean*mean;
  const float rstd=rsqrtf(var+1e-5f);
  float* Lb = L + (((size_t)b)<<12);
  for(int u=t;u<4096;u+=256){
    float x=(a[u]-mean)*rstd*lg[u]+lb[u];
    Lb[u]=leaky(x);
  }
}

// ---------- head: FC (wave-per-output), all-f32 ----------
template<int IN,int OUT,int MODE>
__global__ __launch_bounds__(256) void k_fc(const float* __restrict__ Xin, const float* __restrict__ Wg,
                                            const float* __restrict__ bias, const float* __restrict__ g,
                                            const float* __restrict__ bb, float* __restrict__ out){
  const int gw=(blockIdx.x<<2)+(threadIdx.x>>6);
  const int lane=threadIdx.x&63;
  const int o=gw%OUT, b=gw/OUT;
  constexpr int CHL=IN/64;
  const float* xr = Xin + (size_t)b*IN + lane*CHL;
  const float* wr = Wg  + (size_t)o*IN + lane*CHL;
  float a=0.f;
  #pragma unroll
  for(int c=0;c<CHL;c+=4){
    f32x4 wv=*(const f32x4*)(wr+c);
    f32x4 xv=*(const f32x4*)(xr+c);
    a+=xv.x*wv.x + xv.y*wv.y + xv.z*wv.z + xv.w*wv.w;
  }
  a=wredsum(a);
  if(lane==0){
    float y=a+bias[o];
    if constexpr(MODE<2){
      y=leaky(y*(BNS*g[o])+bb[o]);
    }
    out[(size_t)b*OUT+o]=y;
  }
}

extern "C" void kernel_launch(void* const* d_in, const int* in_sizes, int n_in,
                              void* d_out, int out_size, void* d_ws, size_t ws_size,
                              hipStream_t stream){
  const float* x  =(const float*)d_in[0];
  const float* W1 =(const float*)d_in[1];
  const float* g1 =(const float*)d_in[2];
  const float* b1 =(const float*)d_in[3];
  const float* W2 =(const float*)d_in[4];
  const float* g2 =(const float*)d_in[5];
  const float* b2 =(const float*)d_in[6];
  const float* W3 =(const float*)d_in[7];
  const float* g3 =(const float*)d_in[8];
  const float* b3 =(const float*)d_in[9];
  const float* W4 =(const float*)d_in[10];
  const float* g4 =(const float*)d_in[11];
  const float* b4 =(const float*)d_in[12];
  const float* W5 =(const float*)d_in[13];
  const float* g5 =(const float*)d_in[14];
  const float* b5 =(const float*)d_in[15];
  const float* Watt=(const float*)d_in[16];
  const float* lng=(const float*)d_in[17];
  const float* lnb=(const float*)d_in[18];
  const float* Wl1=(const float*)d_in[19];
  const float* bl1=(const float*)d_in[20];
  const float* g6 =(const float*)d_in[21];
  const float* b6 =(const float*)d_in[22];
  const float* Wl2=(const float*)d_in[23];
  const float* bl2=(const float*)d_in[24];
  const float* g7 =(const float*)d_in[25];
  const float* b7 =(const float*)d_in[26];
  const float* Wl3=(const float*)d_in[27];
  const float* bl3=(const float*)d_in[28];
  char* ws=(char*)d_ws;
  if(ws_size < (size_t)173367296) return;
  float* X0 =(float*)(ws+0);
  float* X1 =(float*)(ws+524288);
  float* X2 =(float*)(ws+8912896);
  float* X3 =(float*)(ws+17301504);
  u16*   H  =(u16*)  (ws+34078720);
  u16*   Hc =(u16*)  (ws+50855936);
  u16*   XP =(u16*)  (ws+84410368);
  u16*   XA1=(u16*)  (ws+84410368);
  u16*   XB1=(u16*)  (ws+86507520);
  float* S  =(float*)(ws+101187584);    // (4,2048,2048) f32 = 64 MB, reused per group
  u16*   X5 =(u16*)  (ws+101187584);    // overlays S (dead by conv5), 64 MB
  float* xx =(float*)(ws+168296448);
  int*   knn=(int*)  (ws+168427520);
  float* Wp1=(float*)(ws+171048960);
  u16*   Wb3=(u16*)  (ws+171057152);
  u16*   Wb4=(u16*)  (ws+171089920);
  u16*   Wb5=(u16*)  (ws+171220992);
  float* Ssc=(float*)(ws+172269568);
  float* att=(float*)(ws+172793856);
  float* L  =(float*)(ws+173056000);
  float* y1 =(float*)(ws+173318144);
  float* y2 =(float*)(ws+173350912);

  k_prep  <<<128,256,0,stream>>>(x,X0);
  k_packw1<<<1,  256,0,stream>>>(W1,Wp1);
  k_w2b   <<<64, 256,0,stream>>>(W3,Wb3,16384);
  k_w2b   <<<256,256,0,stream>>>(W4,Wb4,65536);
  k_w2b   <<<2048,256,0,stream>>>(W5,Wb5,524288);

  // ---- layer 1 (C=3 padded to 4) ----
  k_split1   <<<128,256,0,stream>>>(X0,XA1,XB1);
  k_sqnorm<4><<<128,256,0,stream>>>(X0,xx);
  for(int g=0;g<4;g++){
    k_pdg<32,32,32><<<dim3(16,16,4),256,0,stream>>>(XB1+(size_t)g*8192*32, XA1+(size_t)g*8192*32, S);
    k_selG<<<2048,256,0,stream>>>(S, xx+(size_t)g*8192, knn+(size_t)g*8192*20);
  }
  k_attn<4,32,4><<<512,256,0,stream>>>(X0,knn,H);
  k_vconv<32>   <<<512,256,0,stream>>>(H,Wp1,g1,b1,X1,Hc,0);

  // ---- layer 2 (C=64) ----
  k_split<64>  <<<512,256,0,stream>>>(X1,XP);
  k_sqnorm<64> <<<128,256,0,stream>>>(X1,xx);
  for(int g=0;g<4;g++){
    k_pdg<192,64,128><<<dim3(16,16,4),256,0,stream>>>(XP+(size_t)g*8192*128, XP+(size_t)g*8192*128, S);
    k_selG<<<2048,256,0,stream>>>(S, xx+(size_t)g*8192, knn+(size_t)g*8192*20);
  }
  k_attn<64,128,4><<<512,256,0,stream>>>(X1,knn,H);
  k_vconv<128>    <<<512,256,0,stream>>>(H,W2,g2,b2,X2,Hc,64);

  // ---- layer 3 (C=64 -> O=128) ----
  k_split<64>  <<<512,256,0,stream>>>(X2,XP);
  k_sqnorm<64> <<<128,256,0,stream>>>(X2,xx);
  for(int g=0;g<4;g++){
    k_pdg<192,64,128><<<dim3(16,16,4),256,0,stream>>>(XP+(size_t)g*8192*128, XP+(size_t)g*8192*128, S);
    k_selG<<<2048,256,0,stream>>>(S, xx+(size_t)g*8192, knn+(size_t)g*8192*20);
  }
  k_attn<64,128,4><<<512,256,0,stream>>>(X2,knn,H);
  k_cmfma<128,128,true,512><<<dim3(16,1,16),256,0,stream>>>(Wb3,H,g3,b3,X3,Hc,128);

  // ---- layer 4 (C=128 -> O=256) ----
  k_split<128> <<<512,256,0,stream>>>(X3,XP);
  k_sqnorm<128><<<128,256,0,stream>>>(X3,xx);
  for(int g=0;g<4;g++){
    k_pdg<384,128,256><<<dim3(16,16,4),256,0,stream>>>(XP+(size_t)g*8192*256, XP+(size_t)g*8192*256, S);
    k_selG<<<2048,256,0,stream>>>(S, xx+(size_t)g*8192, knn+(size_t)g*8192*20);
  }
  k_attn<128,256,8><<<1024,256,0,stream>>>(X3,knn,H);
  k_cmfma<256,1,false,512><<<dim3(16,2,16),256,0,stream>>>(Wb4,H,g4,b4,nullptr,Hc,256);

  // ---- conv5 (512 -> 1024) ----
  k_cmfma<512,1,false,1024><<<dim3(16,8,16),256,0,stream>>>(Wb5,Hc,g5,b5,nullptr,X5,0);

  // ---- head ----
  k_scores<<<128,256,0,stream>>>(X5,Watt,Ssc);
  hipMemsetAsync(att,0,16*4096*4,stream);
  k_att   <<<dim3(4,8,16),256,0,stream>>>(X5,Ssc,att);
  k_ln    <<<16,256,0,stream>>>(att,lng,lnb,L);
  k_fc<4096,512,0><<<2048,256,0,stream>>>(L, Wl1,bl1,g6,b6,y1);
  k_fc<512,256,0> <<<1024,256,0,stream>>>(y1,Wl2,bl2,g7,b7,y2);
  k_fc<256,40,2>  <<<160, 256,0,stream>>>(y2,Wl3,bl3,nullptr,nullptr,(float*)d_out);
}

// Round 9
// 1447.878 us; speedup vs baseline: 1.1046x; 1.1046x over previous
//
#include <hip/hip_runtime.h>

#define DEV __device__ __forceinline__

typedef unsigned short u16;
typedef unsigned int   u32;
typedef unsigned long long u64;
typedef float f32x4 __attribute__((ext_vector_type(4)));
typedef __bf16 bf16x8 __attribute__((ext_vector_type(8)));

static constexpr float BNS = 0.9999950000374997f; // 1/sqrt(1+1e-5)

DEV float b2f(u32 s){ union{u32 i; float f;} c; c.i = s<<16; return c.f; }
DEV u16   f2b(float x){ union{float f; u32 i;} c; c.f=x; u32 r=c.i + 0x7fffu + ((c.i>>16)&1u); return (u16)(r>>16); }
DEV float leaky(float x){ return x>0.f ? x : 0.2f*x; }
DEV float wredsum(float v){
  #pragma unroll
  for(int d=32; d; d>>=1) v += __shfl_xor(v, d);
  return v;
}
DEV void gl16(const void* g, void* l){
  __builtin_amdgcn_global_load_lds((const __attribute__((address_space(1))) u32*)g,
                                   (__attribute__((address_space(3))) u32*)l, 16, 0, 0);
}
DEV u64 shflx64(u64 v, int m){
  u32 lo=(u32)v, hi=(u32)(v>>32);
  lo=__shfl_xor(lo,m); hi=__shfl_xor(hi,m);
  return ((u64)hi<<32)|lo;
}
DEV u64 shfl64(u64 v, int src){
  u32 lo=(u32)v, hi=(u32)(v>>32);
  lo=__shfl(lo,src); hi=__shfl(hi,src);
  return ((u64)hi<<32)|lo;
}
// full bitonic sort, descending, 64 lanes
DEV u64 bsort64(u64 k, int lane){
  #pragma unroll
  for(int kk=2; kk<=64; kk<<=1){
    #pragma unroll
    for(int j=kk>>1; j>0; j>>=1){
      u64 o = shflx64(k, j);
      bool km = ((lane & kk)==0) == ((lane & j)==0);
      k = (km == (k > o)) ? k : o;
    }
  }
  return k;
}

// ---------- prep: (B,3,N) f32 -> (B,N,4) f32 (pad 0) ----------
__global__ __launch_bounds__(256) void k_prep(const float* __restrict__ x, float* __restrict__ X0){
  int i = blockIdx.x*256 + threadIdx.x;          // b*N+n, 32768
  int b = i>>11, n = i&2047;
  const float* xb = x + ((size_t)b*3)*2048 + n;
  f32x4 v; v.x=xb[0]; v.y=xb[2048]; v.z=xb[4096]; v.w=0.f;
  ((f32x4*)X0)[i] = v;
}

// ---------- pack W1 (64,6) f32 -> (64,32) f32 matching padded H1 layout ----------
__global__ __launch_bounds__(256) void k_packw1(const float* __restrict__ W1, float* __restrict__ Wp){
  for(int u=threadIdx.x; u<2048; u+=256){
    int o=u>>5, c=u&31;
    float val=0.f;
    if(c<3)            val = W1[o*6+c];
    else if(c>=4&&c<7) val = W1[o*6+3+(c-4)];
    Wp[u]=val;
  }
}

// ---------- pack f32 weight -> bf16 ----------
__global__ __launch_bounds__(256) void k_w2b(const float* __restrict__ W, u16* __restrict__ Wb, int n){
  int i = blockIdx.x*256 + threadIdx.x;
  if(i<n) Wb[i]=f2b(W[i]);
}

// ---------- squared norms ----------
template<int CP>
__global__ __launch_bounds__(256) void k_sqnorm(const float* __restrict__ X, float* __restrict__ xx){
  int i = blockIdx.x*256 + threadIdx.x;
  const f32x4* p = (const f32x4*)(X + (size_t)i*CP);
  f32x4 a4 = {0.f,0.f,0.f,0.f};
  #pragma unroll
  for(int c=0;c<CP/4;c++){ f32x4 v=p[c]; a4 += v*v; }
  xx[i] = (a4.x+a4.y)+(a4.z+a4.w);
}

// ---------- split-bf16 pack: X (B,N,CP f32) -> XP (B,N,2CP bf16) = [h(CP), l(CP)] ----------
template<int CP>
__global__ __launch_bounds__(256) void k_split(const float* __restrict__ X, u16* __restrict__ XP){
  const int gi = blockIdx.x*256 + threadIdx.x;   // 4 threads per point
  const int i = gi>>2, part = gi&3;
  constexpr int CH = CP/4;
  const float* xr = X + (size_t)i*CP + part*CH;
  u16* ph = XP + (size_t)i*(2*CP) + part*CH;
  u16* pl = ph + CP;
  #pragma unroll
  for(int c=0;c<CH;c+=4){
    f32x4 v = *(const f32x4*)(xr+c);
    u16 h0=f2b(v.x),h1=f2b(v.y),h2=f2b(v.z),h3=f2b(v.w);
    ushort4 hh={h0,h1,h2,h3};
    ushort4 ll={f2b(v.x-b2f(h0)),f2b(v.y-b2f(h1)),f2b(v.z-b2f(h2)),f2b(v.w-b2f(h3))};
    *(ushort4*)(ph+c)=hh; *(ushort4*)(pl+c)=ll;
  }
}

// ---------- layer-1 split: X0 (B,N,4) -> XA1=[h,l,h,0..] XB1=[h,h,l,0..] (32 wide) ----------
__global__ __launch_bounds__(256) void k_split1(const float* __restrict__ X0, u16* __restrict__ XA1,
                                                u16* __restrict__ XB1){
  const int i = blockIdx.x*256 + threadIdx.x;
  f32x4 v = ((const f32x4*)X0)[i];
  u16 h0=f2b(v.x),h1=f2b(v.y),h2=f2b(v.z),h3=f2b(v.w);
  ushort4 hh={h0,h1,h2,h3};
  ushort4 ll={f2b(v.x-b2f(h0)),f2b(v.y-b2f(h1)),f2b(v.z-b2f(h2)),f2b(v.w-b2f(h3))};
  ushort4 zz={0,0,0,0};
  u16* a = XA1 + (size_t)i*32;
  u16* b = XB1 + (size_t)i*32;
  *(ushort4*)(a)=hh;  *(ushort4*)(a+4)=ll; *(ushort4*)(a+8)=hh;
  *(ushort4*)(b)=hh;  *(ushort4*)(b+4)=hh; *(ushort4*)(b+8)=ll;
  #pragma unroll
  for(int c=12;c<32;c+=4){ *(ushort4*)(a+c)=zz; *(ushort4*)(b+c)=zz; }
}

// ---------- pd GEMM over 4-batch group: A=queries, B=candidates; XOR-swizzled LDS ----------
template<int KP,int CPM,int STR>
__global__ __launch_bounds__(256) void k_pdg(const u16* __restrict__ Qb, const u16* __restrict__ Cb,
                                             float* __restrict__ Sb){
  __shared__ __align__(16) u16 As[128*32];
  __shared__ __align__(16) u16 Bs[128*32];
  const int tid=threadIdx.x, b=blockIdx.z;       // local batch 0..3
  const int n0=blockIdx.x<<7;                    // query tile base
  const int o0=blockIdx.y<<7;                    // candidate tile base
  const int wid=tid>>6, lane=tid&63, wr=wid>>1, wc=wid&1, lm=lane&15, quad=lane>>4;
  f32x4 acc[4][4];
  #pragma unroll
  for(int a=0;a<4;a++)
    #pragma unroll
    for(int c=0;c<4;c++) acc[a][c]=(f32x4){0.f,0.f,0.f,0.f};
  const int r0=tid>>2;
  const int kcs=(((tid&3)^((r0>>1)&3))<<3);      // swizzled source chunk
  const u16* A0 = Qb + ((size_t)b*2048 + n0 + r0)*STR + kcs;
  const u16* A1 = A0 + (size_t)64*STR;
  const u16* B0 = Cb + ((size_t)b*2048 + o0 + r0)*STR + kcs;
  const u16* B1 = B0 + (size_t)64*STR;
  u16* Aw = As + wid*512;
  u16* Bw = Bs + wid*512;
  const int sw = (lm>>1)&3;
  const int qs = ((quad^sw)<<3);                 // swizzled read chunk
  #pragma unroll
  for(int kk=0;kk<KP/32;kk++){
    const int k0=kk*32;
    const int aoff = (k0<CPM)? k0 : k0-CPM;        // queries: [h,h,l]
    const int boff = (k0<2*CPM)? k0 : k0-2*CPM;    // candidates: [h,l,h]
    __syncthreads();
    gl16(A0+aoff, Aw);  gl16(A1+aoff, Aw+2048);
    gl16(B0+boff, Bw);  gl16(B1+boff, Bw+2048);
    __syncthreads();
    bf16x8 af[4], bfr[4];
    #pragma unroll
    for(int mi=0;mi<4;mi++) af[mi]=*(const bf16x8*)(As + ((wr<<6)+(mi<<4)+lm)*32 + qs);
    #pragma unroll
    for(int ni=0;ni<4;ni++) bfr[ni]=*(const bf16x8*)(Bs + ((wc<<6)+(ni<<4)+lm)*32 + qs);
    #pragma unroll
    for(int mi=0;mi<4;mi++)
      #pragma unroll
      for(int ni=0;ni<4;ni++)
        acc[mi][ni]=__builtin_amdgcn_mfma_f32_16x16x32_bf16(af[mi],bfr[ni],acc[mi][ni],0,0,0);
  }
  // C rows = queries (quad*4+reg), cols = candidates (lm) -> 64B-contiguous stores
  #pragma unroll
  for(int mi=0;mi<4;mi++){
    const int qr = n0 + (wr<<6)+(mi<<4)+(quad<<2);
    #pragma unroll
    for(int ni=0;ni<4;ni++){
      const int cd = o0 + (wc<<6)+(ni<<4)+lm;
      f32x4 cc = acc[mi][ni];
      float* sp = Sb + ((size_t)b*2048 + qr)*2048 + cd;
      sp[0]=cc.x; sp[2048]=cc.y; sp[4096]=cc.z; sp[6144]=cc.w;
    }
  }
}

// ---------- full-row wave-coop top-20 select (primed threshold) ----------
__global__ __launch_bounds__(256) void k_selG(const float* __restrict__ Sb, const float* __restrict__ xxp,
                                              int* __restrict__ knn){
  __shared__ u64 buf[4][320];
  __shared__ u32 cw[4];
  const int w=threadIdx.x>>6, lane=threadIdx.x&63;
  const int row = blockIdx.x*4 + w;      // 0..8191 (4 batches x 2048)
  const int q = row & 2047;
  if(lane==0) cw[w]=0;
  __builtin_amdgcn_wave_barrier();
  __asm__ volatile("s_waitcnt lgkmcnt(0)" ::: "memory");
  const float* Srow = Sb + (size_t)row*2048;
  const float* xxr  = xxp + ((size_t)(row>>11)<<11);
  u64 top=0;
  // ---- prime: exact top-20 of cols 0..255 via 4 sort-merges (no atomics) ----
  {
    const int c0 = lane<<2;
    f32x4 s4=*(const f32x4*)(Srow+c0);
    f32x4 x4=*(const f32x4*)(xxr+c0);
    f32x4 p4=s4+s4-x4;
    #pragma unroll
    for(int e=0;e<4;e++){
      const int col=c0+e;
      u32 u=__float_as_uint(p4[e]);
      u32 mk=u^(u32)(((int)u>>31)|0x80000000u);
      u64 key=((u64)mk<<32)|(u32)(2047-col);
      if(col==q) key=0;
      u64 sb=bsort64(key,lane);
      u64 rev=shfl64(sb,(31-lane)&63);
      u64 c2=(lane<32)?(top>rev?top:rev):0;
      #pragma unroll
      for(int j=16;j>0;j>>=1){
        u64 o=shflx64(c2,j);
        bool km=(lane&j)==0;
        c2=(km==(c2>o))?c2:o;
      }
      top=(lane<20)?c2:0;
    }
  }
  u64 T=shfl64(top,19);
  u32 Thi=(u32)(T>>32);
  u32 um=(Thi&0x80000000u)?(Thi^0x80000000u):(~Thi);
  float Tf=__uint_as_float(um);
  auto flush=[&](){
    __builtin_amdgcn_wave_barrier();
    __asm__ volatile("s_waitcnt lgkmcnt(0)" ::: "memory");
    const int cnt=(int)cw[w];
    __builtin_amdgcn_wave_barrier();
    for(int done=0; done<cnt; done+=64){
      u64 bk = (lane < cnt-done) ? buf[w][done+lane] : 0;
      u64 sb = bsort64(bk, lane);
      u64 rev = shfl64(sb,(31-lane)&63);
      u64 c2 = (lane<32) ? (top>rev?top:rev) : 0;
      #pragma unroll
      for(int j=16;j>0;j>>=1){
        u64 o = shflx64(c2,j);
        bool km=(lane&j)==0;
        c2 = (km==(c2>o))?c2:o;
      }
      top = (lane<20)?c2:0;
    }
    T = shfl64(top,19);
    Thi=(u32)(T>>32);
    u32 um2 = (Thi&0x80000000u)?(Thi^0x80000000u):(~Thi);
    Tf = __uint_as_float(um2);
    if(lane==0) cw[w]=0;
    __builtin_amdgcn_wave_barrier();
    __asm__ volatile("s_waitcnt lgkmcnt(0)" ::: "memory");
  };
  #pragma unroll 1
  for(int g=1;g<8;++g){
    const int c0=g*256 + (lane<<2);
    f32x4 s4=*(const f32x4*)(Srow+c0);
    f32x4 x4=*(const f32x4*)(xxr+c0);
    f32x4 p4=s4+s4-x4;
    int np=(p4.x>=Tf)+(p4.y>=Tf)+(p4.z>=Tf)+(p4.w>=Tf);
    if(__ballot(np!=0)){
      #pragma unroll
      for(int e=0;e<4;e++){
        const int col=c0+e;
        u32 u=__float_as_uint(p4[e]);
        u32 mk=u^(u32)(((int)u>>31)|0x80000000u);
        u64 key=((u64)mk<<32)|(u32)(2047-col);
        if(key>T && col!=q){
          u32 pos=atomicAdd(&cw[w],1u);
          buf[w][pos]=key;
        }
      }
      __builtin_amdgcn_wave_barrier();
      __asm__ volatile("s_waitcnt lgkmcnt(0)" ::: "memory");
      const int c=(int)cw[w];
      if(c>64) flush();
    }
  }
  flush();
  if(lane<20) knn[(size_t)row*20+lane]=2047-(int)(top&0xFFFFFFFFull);
}

// ---------- attention (channel-split, TPP threads/point) ----------
template<int CP,int HS,int TPP>
__global__ __launch_bounds__(256) void k_attn(const float* __restrict__ X, const int* __restrict__ knn,
                                              u16* __restrict__ H){
  constexpr int CH = CP/TPP;
  const int gi = blockIdx.x*256 + threadIdx.x;
  const int i = gi/TPP, t = gi%TPP;
  const float* Xb = X + (((size_t)(i>>11))<<11)*CP;
  const float* q  = X + (size_t)i*CP + t*CH;
  int nb[20];
  { const int* kp = knn + (size_t)i*20;
    #pragma unroll
    for(int j=0;j<20;j++) nb[j]=kp[j]; }
  float qc[CH];
  if constexpr(CH>=4){
    #pragma unroll
    for(int c=0;c<CH;c+=4){
      f32x4 vv = *(const f32x4*)(q+c);
      qc[c]=vv.x; qc[c+1]=vv.y; qc[c+2]=vv.z; qc[c+3]=vv.w;
    }
  } else {
    qc[0]=q[0];
  }
  float s[20];
  #pragma unroll
  for(int j=0;j<20;j++){
    const float* kr = Xb + (size_t)nb[j]*CP + t*CH;
    float a=0.f;
    if constexpr(CH>=4){
      #pragma unroll
      for(int c=0;c<CH;c+=4){
        f32x4 kv = *(const f32x4*)(kr+c);
        a += kv.x*qc[c] + kv.y*qc[c+1] + kv.z*qc[c+2] + kv.w*qc[c+3];
      }
    } else {
      a = qc[0]*kr[0];
    }
    s[j]=a;
  }
  #pragma unroll
  for(int j=0;j<20;j++){
    #pragma unroll
    for(int d=1;d<TPP;d<<=1) s[j] += __shfl_xor(s[j], d);
  }
  float mx=s[0];
  #pragma unroll
  for(int j=1;j<20;j++) mx=fmaxf(mx,s[j]);
  float sum=0.f;
  #pragma unroll
  for(int j=0;j<20;j++){ s[j]=__expf(s[j]-mx); sum+=s[j]; }
  float inv=1.f/sum;
  #pragma unroll
  for(int j=0;j<20;j++) s[j]*=inv;
  float f[CH];
  #pragma unroll
  for(int c=0;c<CH;c++) f[c]=0.f;
  #pragma unroll
  for(int j=0;j<20;j++){
    const float* kr = Xb + (size_t)nb[j]*CP + t*CH;
    const float w = s[j];
    if constexpr(CH>=4){
      #pragma unroll
      for(int c=0;c<CH;c+=4){
        f32x4 kv = *(const f32x4*)(kr+c);
        f[c]+=w*kv.x; f[c+1]+=w*kv.y; f[c+2]+=w*kv.z; f[c+3]+=w*kv.w;
      }
    } else {
      f[0]+=w*kr[0];
    }
  }
  u16* ho = H + (size_t)i*HS;
  if constexpr(CH>=4){
    #pragma unroll
    for(int c=0;c<CH;c+=4){
      ushort4 qsv = {f2b(qc[c]),f2b(qc[c+1]),f2b(qc[c+2]),f2b(qc[c+3])};
      *(ushort4*)(ho + t*CH + c) = qsv;
      ushort4 fs = {f2b(f[c]-qc[c]),f2b(f[c+1]-qc[c+1]),f2b(f[c+2]-qc[c+2]),f2b(f[c+3]-qc[c+3])};
      *(ushort4*)(ho + CP + t*CH + c) = fs;
    }
  } else {
    ho[t]      = f2b(qc[0]);
    ho[CP+t]   = f2b(f[0]-qc[0]);
  }
  if constexpr(HS > 2*CP){
    ushort4 zz={0,0,0,0};
    *(ushort4*)(ho + 2*CP + t*4) = zz;
    if(t < (HS-2*CP-4*TPP)/4) *(ushort4*)(ho + 2*CP + 4*TPP + t*4) = zz;
  }
}

// ---------- vector conv (O=64) ----------
template<int K>
__global__ __launch_bounds__(256) void k_vconv(const u16* __restrict__ H, const float* __restrict__ Wg,
                                               const float* __restrict__ g, const float* __restrict__ bb,
                                               float* __restrict__ Xout, u16* __restrict__ Hc, int hoff){
  __shared__ __align__(16) float Ws[K*64];   // [k][o]
  for(int u=threadIdx.x; u<K*64; u+=256){
    int o=u&63, kk=u>>6;
    Ws[u]=Wg[o*K+kk];
  }
  __syncthreads();
  const int gi = blockIdx.x*256 + threadIdx.x;
  const int i = gi>>2, oc = gi&3;
  const u16* hr = H + (size_t)i*K;
  float acc[16];
  #pragma unroll
  for(int o=0;o<16;o++) acc[o]=0.f;
  for(int k0=0;k0<K;k0+=8){
    uint4 hv = *(const uint4*)(hr+k0);
    float hh[8];
    hh[0]=b2f(hv.x&0xffff); hh[1]=b2f(hv.x>>16);
    hh[2]=b2f(hv.y&0xffff); hh[3]=b2f(hv.y>>16);
    hh[4]=b2f(hv.z&0xffff); hh[5]=b2f(hv.z>>16);
    hh[6]=b2f(hv.w&0xffff); hh[7]=b2f(hv.w>>16);
    #pragma unroll
    for(int kk=0;kk<8;kk++){
      const f32x4* wr = (const f32x4*)(Ws + (k0+kk)*64 + oc*16);
      #pragma unroll
      for(int o4=0;o4<4;o4++){
        f32x4 w = wr[o4];
        acc[o4*4]  +=hh[kk]*w.x; acc[o4*4+1]+=hh[kk]*w.y;
        acc[o4*4+2]+=hh[kk]*w.z; acc[o4*4+3]+=hh[kk]*w.w;
      }
    }
  }
  const int ob = oc*16;
  #pragma unroll
  for(int o=0;o<16;o++) acc[o]=leaky(acc[o]*(BNS*g[ob+o])+bb[ob+o]);
  float* xo = Xout + (size_t)i*64 + ob;
  #pragma unroll
  for(int o=0;o<16;o+=4){ f32x4 sv={acc[o],acc[o+1],acc[o+2],acc[o+3]}; *(f32x4*)(xo+o)=sv; }
  u16* hc = Hc + (size_t)i*512 + hoff + ob;
  #pragma unroll
  for(int o=0;o<16;o+=4){ ushort4 st={f2b(acc[o]),f2b(acc[o+1]),f2b(acc[o+2]),f2b(acc[o+3])}; *(ushort4*)(hc+o)=st; }
}

// ---------- MFMA conv (XOR-swizzled LDS) ----------
template<int K,int OSTR,bool OUT32,int HCS>
__global__ __launch_bounds__(256) void k_cmfma(const u16* __restrict__ Wg, const u16* __restrict__ Hin,
                                               const float* __restrict__ g, const float* __restrict__ bb,
                                               float* __restrict__ Xout, u16* __restrict__ Hc, int hoff){
  __shared__ __align__(16) u16 As[128*32];
  __shared__ __align__(16) u16 Bs[128*32];
  const int tid=threadIdx.x, b=blockIdx.z;
  const int n0=blockIdx.x<<7, o0=blockIdx.y<<7;
  const int wid=tid>>6, lane=tid&63, wr=wid>>1, wc=wid&1, lm=lane&15, quad=lane>>4;
  f32x4 acc[4][4];
  #pragma unroll
  for(int a=0;a<4;a++)
    #pragma unroll
    for(int c=0;c<4;c++) acc[a][c]=(f32x4){0.f,0.f,0.f,0.f};
  const int r0=tid>>2;
  const int kcs=(((tid&3)^((r0>>1)&3))<<3);
  const u16* A0 = Wg + (size_t)(o0+r0)*K + kcs;
  const u16* A1 = A0 + (size_t)64*K;
  const u16* B0 = Hin + ((size_t)b*2048 + n0 + r0)*K + kcs;
  const u16* B1 = B0 + (size_t)64*K;
  u16* Aw = As + wid*512;   // wave-uniform LDS base; HW adds lane*16B
  u16* Bw = Bs + wid*512;
  const int sw = (lm>>1)&3;
  const int qs = ((quad^sw)<<3);
  for(int k0=0;k0<K;k0+=32){
    __syncthreads();
    gl16(A0+k0, Aw);  gl16(A1+k0, Aw+2048);
    gl16(B0+k0, Bw);  gl16(B1+k0, Bw+2048);
    __syncthreads();
    bf16x8 af[4], bfr[4];
    #pragma unroll
    for(int mi=0;mi<4;mi++) af[mi]=*(const bf16x8*)(As + ((wr<<6)+(mi<<4)+lm)*32 + qs);
    #pragma unroll
    for(int ni=0;ni<4;ni++) bfr[ni]=*(const bf16x8*)(Bs + ((wc<<6)+(ni<<4)+lm)*32 + qs);
    #pragma unroll
    for(int mi=0;mi<4;mi++)
      #pragma unroll
      for(int ni=0;ni<4;ni++)
        acc[mi][ni]=__builtin_amdgcn_mfma_f32_16x16x32_bf16(af[mi],bfr[ni],acc[mi][ni],0,0,0);
  }
  #pragma unroll
  for(int mi=0;mi<4;mi++){
    const int o = o0 + (wr<<6) + (mi<<4) + (quad<<2);
    float g0=BNS*g[o],  g1v=BNS*g[o+1], g2v=BNS*g[o+2], g3v=BNS*g[o+3];
    float b0=bb[o], b1v=bb[o+1], b2v=bb[o+2], b3v=bb[o+3];
    #pragma unroll
    for(int ni=0;ni<4;ni++){
      const int n = n0 + (wc<<6) + (ni<<4) + lm;
      const size_t pt = (size_t)b*2048 + n;
      f32x4 cc = acc[mi][ni];
      float y0=leaky(cc.x*g0+b0);
      float y1=leaky(cc.y*g1v+b1v);
      float y2=leaky(cc.z*g2v+b2v);
      float y3=leaky(cc.w*g3v+b3v);
      if constexpr(OUT32){
        f32x4 sv={y0,y1,y2,y3};
        *(f32x4*)(Xout + pt*OSTR + o)=sv;
      }
      ushort4 st={f2b(y0),f2b(y1),f2b(y2),f2b(y3)};
      *(ushort4*)(Hc + pt*HCS + hoff + o)=st;
    }
  }
}

// ---------- head: per-point scores = leaky(x5 . Watt^T) ----------
__global__ __launch_bounds__(256) void k_scores(const u16* __restrict__ X5, const float* __restrict__ Watt,
                                                float* __restrict__ S){
  __shared__ __align__(16) f32x4 Wa[1024];
  for(int u=threadIdx.x; u<1024; u+=256){
    f32x4 w; w.x=Watt[u]; w.y=Watt[1024+u]; w.z=Watt[2048+u]; w.w=Watt[3072+u];
    Wa[u]=w;
  }
  __syncthreads();
  const int i = blockIdx.x*256 + threadIdx.x;
  const u16* xr = X5 + (size_t)i*1024;
  f32x4 a={0.f,0.f,0.f,0.f};
  for(int k0=0;k0<1024;k0+=8){
    uint4 hv=*(const uint4*)(xr+k0);
    float hh[8];
    hh[0]=b2f(hv.x&0xffff); hh[1]=b2f(hv.x>>16);
    hh[2]=b2f(hv.y&0xffff); hh[3]=b2f(hv.y>>16);
    hh[4]=b2f(hv.z&0xffff); hh[5]=b2f(hv.z>>16);
    hh[6]=b2f(hv.w&0xffff); hh[7]=b2f(hv.w>>16);
    #pragma unroll
    for(int kk=0;kk<8;kk++){
      f32x4 w=Wa[k0+kk];
      a.x+=hh[kk]*w.x; a.y+=hh[kk]*w.y; a.z+=hh[kk]*w.z; a.w+=hh[kk]*w.w;
    }
  }
  f32x4 sv={leaky(a.x),leaky(a.y),leaky(a.z),leaky(a.w)};
  ((f32x4*)S)[i]=sv;
}

// ---------- head: att[b,h,e] = sum_n x5[b,n,e]*S[b,n,h] (atomic partials) ----------
__global__ __launch_bounds__(256) void k_att(const u16* __restrict__ X5, const float* __restrict__ S,
                                             float* __restrict__ att){
  __shared__ __align__(16) f32x4 Sh[256];
  const int b=blockIdx.z, e=(blockIdx.x<<8)+threadIdx.x, nbase=blockIdx.y<<8;
  Sh[threadIdx.x]=((const f32x4*)S)[(((size_t)b)<<11)+nbase+threadIdx.x];
  __syncthreads();
  f32x4 a={0.f,0.f,0.f,0.f};
  const u16* xp = X5 + ((((size_t)b)<<11)+nbase)*1024 + e;
  for(int nn=0;nn<256;nn++){
    float xv=b2f(xp[(size_t)nn*1024]);
    f32x4 s=Sh[nn];
    a.x+=xv*s.x; a.y+=xv*s.y; a.z+=xv*s.z; a.w+=xv*s.w;
  }
  float* ab = att + (((size_t)b)<<12) + e;
  atomicAdd(ab,      a.x); atomicAdd(ab+1024, a.y);
  atomicAdd(ab+2048, a.z); atomicAdd(ab+3072, a.w);
}

// ---------- head: layernorm + leaky ----------
__global__ __launch_bounds__(256) void k_ln(const float* __restrict__ att, const float* __restrict__ lg,
                                            const float* __restrict__ lb, float* __restrict__ L){
  const int b=blockIdx.x, t=threadIdx.x;
  const float* a = att + (((size_t)b)<<12);
  float s=0.f, sq=0.f;
  for(int u=t;u<4096;u+=256){ float x=a[u]; s+=x; sq+=x*x; }
  s=wredsum(s); sq=wredsum(sq);
  __shared__ float rs[4], rq[4];
  const int wid=t>>6, lane=t&63;
  if(lane==0){ rs[wid]=s; rq[wid]=sq; }
  __syncthreads();
  s=rs[0]+rs[1]+rs[2]+rs[3];
  sq=rq[0]+rq[1]+rq[2]+rq[3];
  const float mean=s*(1.f/4096.f);
  const float var=sq*(1.f/4096.f)-mean*mean;
  const float rstd=rsqrtf(var+1e-5f);
  float* Lb = L + (((size_t)b)<<12);
  for(int u=t;u<4096;u+=256){
    float x=(a[u]-mean)*rstd*lg[u]+lb[u];
    Lb[u]=leaky(x);
  }
}

// ---------- head: FC (wave-per-output), all-f32 ----------
template<int IN,int OUT,int MODE>
__global__ __launch_bounds__(256) void k_fc(const float* __restrict__ Xin, const float* __restrict__ Wg,
                                            const float* __restrict__ bias, const float* __restrict__ g,
                                            const float* __restrict__ bb, float* __restrict__ out){
  const int gw=(blockIdx.x<<2)+(threadIdx.x>>6);
  const int lane=threadIdx.x&63;
  const int o=gw%OUT, b=gw/OUT;
  constexpr int CHL=IN/64;
  const float* xr = Xin + (size_t)b*IN + lane*CHL;
  const float* wr = Wg  + (size_t)o*IN + lane*CHL;
  float a=0.f;
  #pragma unroll
  for(int c=0;c<CHL;c+=4){
    f32x4 wv=*(const f32x4*)(wr+c);
    f32x4 xv=*(const f32x4*)(xr+c);
    a+=xv.x*wv.x + xv.y*wv.y + xv.z*wv.z + xv.w*wv.w;
  }
  a=wredsum(a);
  if(lane==0){
    float y=a+bias[o];
    if constexpr(MODE<2){
      y=leaky(y*(BNS*g[o])+bb[o]);
    }
    out[(size_t)b*OUT+o]=y;
  }
}

extern "C" void kernel_launch(void* const* d_in, const int* in_sizes, int n_in,
                              void* d_out, int out_size, void* d_ws, size_t ws_size,
                              hipStream_t stream){
  const float* x  =(const float*)d_in[0];
  const float* W1 =(const float*)d_in[1];
  const float* g1 =(const float*)d_in[2];
  const float* b1 =(const float*)d_in[3];
  const float* W2 =(const float*)d_in[4];
  const float* g2 =(const float*)d_in[5];
  const float* b2 =(const float*)d_in[6];
  const float* W3 =(const float*)d_in[7];
  const float* g3 =(const float*)d_in[8];
  const float* b3 =(const float*)d_in[9];
  const float* W4 =(const float*)d_in[10];
  const float* g4 =(const float*)d_in[11];
  const float* b4 =(const float*)d_in[12];
  const float* W5 =(const float*)d_in[13];
  const float* g5 =(const float*)d_in[14];
  const float* b5 =(const float*)d_in[15];
  const float* Watt=(const float*)d_in[16];
  const float* lng=(const float*)d_in[17];
  const float* lnb=(const float*)d_in[18];
  const float* Wl1=(const float*)d_in[19];
  const float* bl1=(const float*)d_in[20];
  const float* g6 =(const float*)d_in[21];
  const float* b6 =(const float*)d_in[22];
  const float* Wl2=(const float*)d_in[23];
  const float* bl2=(const float*)d_in[24];
  const float* g7 =(const float*)d_in[25];
  const float* b7 =(const float*)d_in[26];
  const float* Wl3=(const float*)d_in[27];
  const float* bl3=(const float*)d_in[28];
  char* ws=(char*)d_ws;
  if(ws_size < (size_t)173367296) return;
  float* X0 =(float*)(ws+0);
  float* X1 =(float*)(ws+524288);
  float* X2 =(float*)(ws+8912896);
  float* X3 =(float*)(ws+17301504);
  u16*   H  =(u16*)  (ws+34078720);
  u16*   Hc =(u16*)  (ws+50855936);
  u16*   XP =(u16*)  (ws+84410368);
  u16*   XA1=(u16*)  (ws+84410368);
  u16*   XB1=(u16*)  (ws+86507520);
  float* S  =(float*)(ws+101187584);    // (4,2048,2048) f32 = 64 MB, reused per group
  u16*   X5 =(u16*)  (ws+101187584);    // overlays S (dead by conv5), 64 MB
  float* xx =(float*)(ws+168296448);
  int*   knn=(int*)  (ws+168427520);
  float* Wp1=(float*)(ws+171048960);
  u16*   Wb3=(u16*)  (ws+171057152);
  u16*   Wb4=(u16*)  (ws+171089920);
  u16*   Wb5=(u16*)  (ws+171220992);
  float* Ssc=(float*)(ws+172269568);
  float* att=(float*)(ws+172793856);
  float* L  =(float*)(ws+173056000);
  float* y1 =(float*)(ws+173318144);
  float* y2 =(float*)(ws+173350912);

  k_prep  <<<128,256,0,stream>>>(x,X0);
  k_packw1<<<1,  256,0,stream>>>(W1,Wp1);
  k_w2b   <<<64, 256,0,stream>>>(W3,Wb3,16384);
  k_w2b   <<<256,256,0,stream>>>(W4,Wb4,65536);
  k_w2b   <<<2048,256,0,stream>>>(W5,Wb5,524288);

  // ---- layer 1 (C=3 padded to 4) ----
  k_split1   <<<128,256,0,stream>>>(X0,XA1,XB1);
  k_sqnorm<4><<<128,256,0,stream>>>(X0,xx);
  for(int g=0;g<4;g++){
    k_pdg<32,32,32><<<dim3(16,16,4),256,0,stream>>>(XB1+(size_t)g*8192*32, XA1+(size_t)g*8192*32, S);
    k_selG<<<2048,256,0,stream>>>(S, xx+(size_t)g*8192, knn+(size_t)g*8192*20);
  }
  k_attn<4,32,4><<<512,256,0,stream>>>(X0,knn,H);
  k_vconv<32>   <<<512,256,0,stream>>>(H,Wp1,g1,b1,X1,Hc,0);

  // ---- layer 2 (C=64) ----
  k_split<64>  <<<512,256,0,stream>>>(X1,XP);
  k_sqnorm<64> <<<128,256,0,stream>>>(X1,xx);
  for(int g=0;g<4;g++){
    k_pdg<192,64,128><<<dim3(16,16,4),256,0,stream>>>(XP+(size_t)g*8192*128, XP+(size_t)g*8192*128, S);
    k_selG<<<2048,256,0,stream>>>(S, xx+(size_t)g*8192, knn+(size_t)g*8192*20);
  }
  k_attn<64,128,4><<<512,256,0,stream>>>(X1,knn,H);
  k_vconv<128>    <<<512,256,0,stream>>>(H,W2,g2,b2,X2,Hc,64);

  // ---- layer 3 (C=64 -> O=128) ----
  k_split<64>  <<<512,256,0,stream>>>(X2,XP);
  k_sqnorm<64> <<<128,256,0,stream>>>(X2,xx);
  for(int g=0;g<4;g++){
    k_pdg<192,64,128><<<dim3(16,16,4),256,0,stream>>>(XP+(size_t)g*8192*128, XP+(size_t)g*8192*128, S);
    k_selG<<<2048,256,0,stream>>>(S, xx+(size_t)g*8192, knn+(size_t)g*8192*20);
  }
  k_attn<64,128,4><<<512,256,0,stream>>>(X2,knn,H);
  k_cmfma<128,128,true,512><<<dim3(16,1,16),256,0,stream>>>(Wb3,H,g3,b3,X3,Hc,128);

  // ---- layer 4 (C=128 -> O=256) ----
  k_split<128> <<<512,256,0,stream>>>(X3,XP);
  k_sqnorm<128><<<128,256,0,stream>>>(X3,xx);
  for(int g=0;g<4;g++){
    k_pdg<384,128,256><<<dim3(16,16,4),256,0,stream>>>(XP+(size_t)g*8192*256, XP+(size_t)g*8192*256, S);
    k_selG<<<2048,256,0,stream>>>(S, xx+(size_t)g*8192, knn+(size_t)g*8192*20);
  }
  k_attn<128,256,8><<<1024,256,0,stream>>>(X3,knn,H);
  k_cmfma<256,1,false,512><<<dim3(16,2,16),256,0,stream>>>(Wb4,H,g4,b4,nullptr,Hc,256);

  // ---- conv5 (512 -> 1024) ----
  k_cmfma<512,1,false,1024><<<dim3(16,8,16),256,0,stream>>>(Wb5,Hc,g5,b5,nullptr,X5,0);

  // ---- head ----
  k_scores<<<128,256,0,stream>>>(X5,Watt,Ssc);
  hipMemsetAsync(att,0,16*4096*4,stream);
  k_att   <<<dim3(4,8,16),256,0,stream>>>(X5,Ssc,att);
  k_ln    <<<16,256,0,stream>>>(att,lng,lnb,L);
  k_fc<4096,512,0><<<2048,256,0,stream>>>(L, Wl1,bl1,g6,b6,y1);
  k_fc<512,256,0> <<<1024,256,0,stream>>>(y1,Wl2,bl2,g7,b7,y2);
  k_fc<256,40,2>  <<<160, 256,0,stream>>>(y2,Wl3,bl3,nullptr,nullptr,(float*)d_out);
}

// Round 10
// 1209.082 us; speedup vs baseline: 1.3227x; 1.1975x over previous
//
#include <hip/hip_runtime.h>

#define DEV __device__ __forceinline__

typedef unsigned short u16;
typedef unsigned int   u32;
typedef unsigned long long u64;
typedef float f32x4 __attribute__((ext_vector_type(4)));
typedef __bf16 bf16x8 __attribute__((ext_vector_type(8)));

static constexpr float BNS = 0.9999950000374997f; // 1/sqrt(1+1e-5)

DEV float b2f(u32 s){ union{u32 i; float f;} c; c.i = s<<16; return c.f; }
DEV u16   f2b(float x){ union{float f; u32 i;} c; c.f=x; u32 r=c.i + 0x7fffu + ((c.i>>16)&1u); return (u16)(r>>16); }
DEV float leaky(float x){ return x>0.f ? x : 0.2f*x; }
DEV float wredsum(float v){
  #pragma unroll
  for(int d=32; d; d>>=1) v += __shfl_xor(v, d);
  return v;
}
DEV void gl16(const void* g, void* l){
  __builtin_amdgcn_global_load_lds((const __attribute__((address_space(1))) u32*)g,
                                   (__attribute__((address_space(3))) u32*)l, 16, 0, 0);
}
DEV u64 shflx64(u64 v, int m){
  u32 lo=(u32)v, hi=(u32)(v>>32);
  lo=__shfl_xor(lo,m); hi=__shfl_xor(hi,m);
  return ((u64)hi<<32)|lo;
}
DEV u64 shfl64(u64 v, int src){
  u32 lo=(u32)v, hi=(u32)(v>>32);
  lo=__shfl(lo,src); hi=__shfl(hi,src);
  return ((u64)hi<<32)|lo;
}
// full bitonic sort, descending, 64 lanes
DEV u64 bsort64(u64 k, int lane){
  #pragma unroll
  for(int kk=2; kk<=64; kk<<=1){
    #pragma unroll
    for(int j=kk>>1; j>0; j>>=1){
      u64 o = shflx64(k, j);
      bool km = ((lane & kk)==0) == ((lane & j)==0);
      k = (km == (k > o)) ? k : o;
    }
  }
  return k;
}

// ---------- fused prep: x(B,3,N) -> X0(B,N,4) + XA1/XB1 split packs + xx ----------
__global__ __launch_bounds__(256) void k_prep0(const float* __restrict__ x, float* __restrict__ X0,
                                               u16* __restrict__ XA1, u16* __restrict__ XB1,
                                               float* __restrict__ xx){
  int i = blockIdx.x*256 + threadIdx.x;          // b*N+n, 32768
  int b = i>>11, n = i&2047;
  const float* xb = x + ((size_t)b*3)*2048 + n;
  float vx=xb[0], vy=xb[2048], vz=xb[4096];
  f32x4 v; v.x=vx; v.y=vy; v.z=vz; v.w=0.f;
  ((f32x4*)X0)[i] = v;
  xx[i] = (vx*vx+vy*vy)+vz*vz;
  u16 h0=f2b(vx),h1=f2b(vy),h2=f2b(vz),h3=0;
  ushort4 hh={h0,h1,h2,h3};
  ushort4 ll={f2b(vx-b2f(h0)),f2b(vy-b2f(h1)),f2b(vz-b2f(h2)),0};
  ushort4 zz={0,0,0,0};
  u16* a = XA1 + (size_t)i*32;
  u16* bp = XB1 + (size_t)i*32;
  *(ushort4*)(a)=hh;  *(ushort4*)(a+4)=ll; *(ushort4*)(a+8)=hh;
  *(ushort4*)(bp)=hh; *(ushort4*)(bp+4)=hh; *(ushort4*)(bp+8)=ll;
  #pragma unroll
  for(int c=12;c<32;c+=4){ *(ushort4*)(a+c)=zz; *(ushort4*)(bp+c)=zz; }
}

// ---------- pack W1 (64,6) f32 -> (64,32) f32 matching padded H1 layout ----------
__global__ __launch_bounds__(256) void k_packw1(const float* __restrict__ W1, float* __restrict__ Wp){
  for(int u=threadIdx.x; u<2048; u+=256){
    int o=u>>5, c=u&31;
    float val=0.f;
    if(c<3)            val = W1[o*6+c];
    else if(c>=4&&c<7) val = W1[o*6+3+(c-4)];
    Wp[u]=val;
  }
}

// ---------- pack all conv weights f32 -> bf16 in one dispatch ----------
__global__ __launch_bounds__(256) void k_w2bAll(const float* __restrict__ W3, const float* __restrict__ W4,
                                                const float* __restrict__ W5, u16* __restrict__ Wb3,
                                                u16* __restrict__ Wb4, u16* __restrict__ Wb5){
  int i = blockIdx.x*256 + threadIdx.x;          // 606208 total
  if(i<16384)       Wb3[i]=f2b(W3[i]);
  else if(i<81920)  Wb4[i-16384]=f2b(W4[i-16384]);
  else if(i<606208) Wb5[i-81920]=f2b(W5[i-81920]);
}

// ---------- split-bf16 pack + fused sqnorm ----------
template<int CP>
__global__ __launch_bounds__(256) void k_split(const float* __restrict__ X, u16* __restrict__ XP,
                                               float* __restrict__ xx){
  const int gi = blockIdx.x*256 + threadIdx.x;   // 4 threads per point
  const int i = gi>>2, part = gi&3;
  constexpr int CH = CP/4;
  const float* xr = X + (size_t)i*CP + part*CH;
  u16* ph = XP + (size_t)i*(2*CP) + part*CH;
  u16* pl = ph + CP;
  f32x4 a4 = {0.f,0.f,0.f,0.f};
  #pragma unroll
  for(int c=0;c<CH;c+=4){
    f32x4 v = *(const f32x4*)(xr+c);
    a4 += v*v;
    u16 h0=f2b(v.x),h1=f2b(v.y),h2=f2b(v.z),h3=f2b(v.w);
    ushort4 hh={h0,h1,h2,h3};
    ushort4 ll={f2b(v.x-b2f(h0)),f2b(v.y-b2f(h1)),f2b(v.z-b2f(h2)),f2b(v.w-b2f(h3))};
    *(ushort4*)(ph+c)=hh; *(ushort4*)(pl+c)=ll;
  }
  float s=(a4.x+a4.y)+(a4.z+a4.w);
  s += __shfl_xor(s,1);
  s += __shfl_xor(s,2);
  if(part==0) xx[i]=s;
}

// ---------- pd GEMM over 4-batch group; stores p = 2s - xx[col]; XOR-swizzled LDS ----------
template<int KP,int CPM,int STR>
__global__ __launch_bounds__(256) void k_pdg(const u16* __restrict__ Qb, const u16* __restrict__ Cb,
                                             const float* __restrict__ xxg, float* __restrict__ Sb){
  __shared__ __align__(16) u16 As[128*32];
  __shared__ __align__(16) u16 Bs[128*32];
  const int tid=threadIdx.x, b=blockIdx.z;       // local batch 0..3
  const int n0=blockIdx.x<<7;                    // query tile base
  const int o0=blockIdx.y<<7;                    // candidate tile base
  const int wid=tid>>6, lane=tid&63, wr=wid>>1, wc=wid&1, lm=lane&15, quad=lane>>4;
  f32x4 acc[4][4];
  #pragma unroll
  for(int a=0;a<4;a++)
    #pragma unroll
    for(int c=0;c<4;c++) acc[a][c]=(f32x4){0.f,0.f,0.f,0.f};
  const int r0=tid>>2;
  const int kcs=(((tid&3)^((r0>>1)&3))<<3);      // swizzled source chunk
  const u16* A0 = Qb + ((size_t)b*2048 + n0 + r0)*STR + kcs;
  const u16* A1 = A0 + (size_t)64*STR;
  const u16* B0 = Cb + ((size_t)b*2048 + o0 + r0)*STR + kcs;
  const u16* B1 = B0 + (size_t)64*STR;
  u16* Aw = As + wid*512;
  u16* Bw = Bs + wid*512;
  const int sw = (lm>>1)&3;
  const int qs = ((quad^sw)<<3);                 // swizzled read chunk
  #pragma unroll
  for(int kk=0;kk<KP/32;kk++){
    const int k0=kk*32;
    const int aoff = (k0<CPM)? k0 : k0-CPM;        // queries: [h,h,l]
    const int boff = (k0<2*CPM)? k0 : k0-2*CPM;    // candidates: [h,l,h]
    __syncthreads();
    gl16(A0+aoff, Aw);  gl16(A1+aoff, Aw+2048);
    gl16(B0+boff, Bw);  gl16(B1+boff, Bw+2048);
    __syncthreads();
    bf16x8 af[4], bfr[4];
    #pragma unroll
    for(int mi=0;mi<4;mi++) af[mi]=*(const bf16x8*)(As + ((wr<<6)+(mi<<4)+lm)*32 + qs);
    #pragma unroll
    for(int ni=0;ni<4;ni++) bfr[ni]=*(const bf16x8*)(Bs + ((wc<<6)+(ni<<4)+lm)*32 + qs);
    #pragma unroll
    for(int mi=0;mi<4;mi++)
      #pragma unroll
      for(int ni=0;ni<4;ni++)
        acc[mi][ni]=__builtin_amdgcn_mfma_f32_16x16x32_bf16(af[mi],bfr[ni],acc[mi][ni],0,0,0);
  }
  float xn[4];
  #pragma unroll
  for(int ni=0;ni<4;ni++){
    const int cd = o0 + (wc<<6)+(ni<<4)+lm;
    xn[ni] = xxg[(size_t)b*2048 + cd];
  }
  #pragma unroll
  for(int mi=0;mi<4;mi++){
    const int qr = n0 + (wr<<6)+(mi<<4)+(quad<<2);
    #pragma unroll
    for(int ni=0;ni<4;ni++){
      const int cd = o0 + (wc<<6)+(ni<<4)+lm;
      f32x4 cc = acc[mi][ni];
      float* sp = Sb + ((size_t)b*2048 + qr)*2048 + cd;
      sp[0]   = cc.x+cc.x-xn[ni];
      sp[2048]= cc.y+cc.y-xn[ni];
      sp[4096]= cc.z+cc.z-xn[ni];
      sp[6144]= cc.w+cc.w-xn[ni];
    }
  }
}

// ---------- full-row wave-coop top-20 select, kNN-warm-start prime ----------
template<bool L1>
__global__ __launch_bounds__(256) void k_selG(const float* __restrict__ Sb, int* __restrict__ knn){
  __shared__ u64 buf[4][320];
  __shared__ u32 cw[4];
  const int w=threadIdx.x>>6, lane=threadIdx.x&63;
  const int row = blockIdx.x*4 + w;      // 0..8191 (4 batches x 2048)
  const int q = row & 2047;
  if(lane==0) cw[w]=0;
  __builtin_amdgcn_wave_barrier();
  __asm__ volatile("s_waitcnt lgkmcnt(0)" ::: "memory");
  const float* Srow = Sb + (size_t)row*2048;
  // ---- prime: threshold = 20th-best of 20 real candidates ----
  int pc;
  if constexpr(L1) pc = (q + 1 + lane) & 2047;                 // arbitrary distinct cols != q
  else             pc = (lane<20) ? knn[(size_t)row*20+lane] : q;  // prev-layer kNN
  float pv = Srow[pc];
  u64 pkey;
  { u32 u=__float_as_uint(pv);
    u32 mk=u^(u32)(((int)u>>31)|0x80000000u);
    pkey=((u64)mk<<32)|(u32)(2047-pc); }
  if(lane>=20) pkey=0;
  pkey = bsort64(pkey,lane);
  u64 top=0;
  u64 T = shfl64(pkey,19);
  u32 Thi=(u32)(T>>32);
  u32 um=(Thi&0x80000000u)?(Thi^0x80000000u):(~Thi);
  float Tf=__uint_as_float(um);
  auto flush=[&](){
    __builtin_amdgcn_wave_barrier();
    __asm__ volatile("s_waitcnt lgkmcnt(0)" ::: "memory");
    const int cnt=(int)cw[w];
    __builtin_amdgcn_wave_barrier();
    for(int done=0; done<cnt; done+=64){
      u64 bk = (lane < cnt-done) ? buf[w][done+lane] : 0;
      u64 sb = bsort64(bk, lane);
      u64 rev = shfl64(sb,(31-lane)&63);
      u64 c2 = (lane<32) ? (top>rev?top:rev) : 0;
      #pragma unroll
      for(int j=16;j>0;j>>=1){
        u64 o = shflx64(c2,j);
        bool km=(lane&j)==0;
        c2 = (km==(c2>o))?c2:o;
      }
      top = (lane<20)?c2:0;
    }
    T = shfl64(top,19);
    Thi=(u32)(T>>32);
    u32 um2 = (Thi&0x80000000u)?(Thi^0x80000000u):(~Thi);
    Tf = __uint_as_float(um2);
    if(lane==0) cw[w]=0;
    __builtin_amdgcn_wave_barrier();
    __asm__ volatile("s_waitcnt lgkmcnt(0)" ::: "memory");
  };
  #pragma unroll 1
  for(int g=0;g<8;++g){
    const int c0=g*256 + (lane<<2);
    f32x4 p4=*(const f32x4*)(Srow+c0);
    int np=(p4.x>=Tf)+(p4.y>=Tf)+(p4.z>=Tf)+(p4.w>=Tf);
    if(__ballot(np!=0)){
      #pragma unroll
      for(int e=0;e<4;e++){
        const int col=c0+e;
        u32 u=__float_as_uint(p4[e]);
        u32 mk=u^(u32)(((int)u>>31)|0x80000000u);
        u64 key=((u64)mk<<32)|(u32)(2047-col);
        if(key>=T && col!=q){
          u32 pos=atomicAdd(&cw[w],1u);
          buf[w][pos]=key;
        }
      }
      __builtin_amdgcn_wave_barrier();
      __asm__ volatile("s_waitcnt lgkmcnt(0)" ::: "memory");
      const int c=(int)cw[w];
      if(c>64) flush();
    }
  }
  flush();
  if(lane<20) knn[(size_t)row*20+lane]=2047-(int)(top&0xFFFFFFFFull);
}

// ---------- attention (channel-split, TPP threads/point) ----------
template<int CP,int HS,int TPP>
__global__ __launch_bounds__(256) void k_attn(const float* __restrict__ X, const int* __restrict__ knn,
                                              u16* __restrict__ H){
  constexpr int CH = CP/TPP;
  const int gi = blockIdx.x*256 + threadIdx.x;
  const int i = gi/TPP, t = gi%TPP;
  const float* Xb = X + (((size_t)(i>>11))<<11)*CP;
  const float* q  = X + (size_t)i*CP + t*CH;
  int nb[20];
  { const int* kp = knn + (size_t)i*20;
    #pragma unroll
    for(int j=0;j<20;j++) nb[j]=kp[j]; }
  float qc[CH];
  if constexpr(CH>=4){
    #pragma unroll
    for(int c=0;c<CH;c+=4){
      f32x4 vv = *(const f32x4*)(q+c);
      qc[c]=vv.x; qc[c+1]=vv.y; qc[c+2]=vv.z; qc[c+3]=vv.w;
    }
  } else {
    qc[0]=q[0];
  }
  float s[20];
  #pragma unroll
  for(int j=0;j<20;j++){
    const float* kr = Xb + (size_t)nb[j]*CP + t*CH;
    float a=0.f;
    if constexpr(CH>=4){
      #pragma unroll
      for(int c=0;c<CH;c+=4){
        f32x4 kv = *(const f32x4*)(kr+c);
        a += kv.x*qc[c] + kv.y*qc[c+1] + kv.z*qc[c+2] + kv.w*qc[c+3];
      }
    } else {
      a = qc[0]*kr[0];
    }
    s[j]=a;
  }
  #pragma unroll
  for(int j=0;j<20;j++){
    #pragma unroll
    for(int d=1;d<TPP;d<<=1) s[j] += __shfl_xor(s[j], d);
  }
  float mx=s[0];
  #pragma unroll
  for(int j=1;j<20;j++) mx=fmaxf(mx,s[j]);
  float sum=0.f;
  #pragma unroll
  for(int j=0;j<20;j++){ s[j]=__expf(s[j]-mx); sum+=s[j]; }
  float inv=1.f/sum;
  #pragma unroll
  for(int j=0;j<20;j++) s[j]*=inv;
  float f[CH];
  #pragma unroll
  for(int c=0;c<CH;c++) f[c]=0.f;
  #pragma unroll
  for(int j=0;j<20;j++){
    const float* kr = Xb + (size_t)nb[j]*CP + t*CH;
    const float w = s[j];
    if constexpr(CH>=4){
      #pragma unroll
      for(int c=0;c<CH;c+=4){
        f32x4 kv = *(const f32x4*)(kr+c);
        f[c]+=w*kv.x; f[c+1]+=w*kv.y; f[c+2]+=w*kv.z; f[c+3]+=w*kv.w;
      }
    } else {
      f[0]+=w*kr[0];
    }
  }
  u16* ho = H + (size_t)i*HS;
  if constexpr(CH>=4){
    #pragma unroll
    for(int c=0;c<CH;c+=4){
      ushort4 qsv = {f2b(qc[c]),f2b(qc[c+1]),f2b(qc[c+2]),f2b(qc[c+3])};
      *(ushort4*)(ho + t*CH + c) = qsv;
      ushort4 fs = {f2b(f[c]-qc[c]),f2b(f[c+1]-qc[c+1]),f2b(f[c+2]-qc[c+2]),f2b(f[c+3]-qc[c+3])};
      *(ushort4*)(ho + CP + t*CH + c) = fs;
    }
  } else {
    ho[t]      = f2b(qc[0]);
    ho[CP+t]   = f2b(f[0]-qc[0]);
  }
  if constexpr(HS > 2*CP){
    ushort4 zz={0,0,0,0};
    *(ushort4*)(ho + 2*CP + t*4) = zz;
    if(t < (HS-2*CP-4*TPP)/4) *(ushort4*)(ho + 2*CP + 4*TPP + t*4) = zz;
  }
}

// ---------- vector conv (O=64) ----------
template<int K>
__global__ __launch_bounds__(256) void k_vconv(const u16* __restrict__ H, const float* __restrict__ Wg,
                                               const float* __restrict__ g, const float* __restrict__ bb,
                                               float* __restrict__ Xout, u16* __restrict__ Hc, int hoff){
  __shared__ __align__(16) float Ws[K*64];   // [k][o]
  for(int u=threadIdx.x; u<K*64; u+=256){
    int o=u&63, kk=u>>6;
    Ws[u]=Wg[o*K+kk];
  }
  __syncthreads();
  const int gi = blockIdx.x*256 + threadIdx.x;
  const int i = gi>>2, oc = gi&3;
  const u16* hr = H + (size_t)i*K;
  float acc[16];
  #pragma unroll
  for(int o=0;o<16;o++) acc[o]=0.f;
  for(int k0=0;k0<K;k0+=8){
    uint4 hv = *(const uint4*)(hr+k0);
    float hh[8];
    hh[0]=b2f(hv.x&0xffff); hh[1]=b2f(hv.x>>16);
    hh[2]=b2f(hv.y&0xffff); hh[3]=b2f(hv.y>>16);
    hh[4]=b2f(hv.z&0xffff); hh[5]=b2f(hv.z>>16);
    hh[6]=b2f(hv.w&0xffff); hh[7]=b2f(hv.w>>16);
    #pragma unroll
    for(int kk=0;kk<8;kk++){
      const f32x4* wr = (const f32x4*)(Ws + (k0+kk)*64 + oc*16);
      #pragma unroll
      for(int o4=0;o4<4;o4++){
        f32x4 w = wr[o4];
        acc[o4*4]  +=hh[kk]*w.x; acc[o4*4+1]+=hh[kk]*w.y;
        acc[o4*4+2]+=hh[kk]*w.z; acc[o4*4+3]+=hh[kk]*w.w;
      }
    }
  }
  const int ob = oc*16;
  #pragma unroll
  for(int o=0;o<16;o++) acc[o]=leaky(acc[o]*(BNS*g[ob+o])+bb[ob+o]);
  float* xo = Xout + (size_t)i*64 + ob;
  #pragma unroll
  for(int o=0;o<16;o+=4){ f32x4 sv={acc[o],acc[o+1],acc[o+2],acc[o+3]}; *(f32x4*)(xo+o)=sv; }
  u16* hc = Hc + (size_t)i*512 + hoff + ob;
  #pragma unroll
  for(int o=0;o<16;o+=4){ ushort4 st={f2b(acc[o]),f2b(acc[o+1]),f2b(acc[o+2]),f2b(acc[o+3])}; *(ushort4*)(hc+o)=st; }
}

// ---------- MFMA conv (XOR-swizzled LDS) ----------
template<int K,int OSTR,bool OUT32,int HCS>
__global__ __launch_bounds__(256) void k_cmfma(const u16* __restrict__ Wg, const u16* __restrict__ Hin,
                                               const float* __restrict__ g, const float* __restrict__ bb,
                                               float* __restrict__ Xout, u16* __restrict__ Hc, int hoff){
  __shared__ __align__(16) u16 As[128*32];
  __shared__ __align__(16) u16 Bs[128*32];
  const int tid=threadIdx.x, b=blockIdx.z;
  const int n0=blockIdx.x<<7, o0=blockIdx.y<<7;
  const int wid=tid>>6, lane=tid&63, wr=wid>>1, wc=wid&1, lm=lane&15, quad=lane>>4;
  f32x4 acc[4][4];
  #pragma unroll
  for(int a=0;a<4;a++)
    #pragma unroll
    for(int c=0;c<4;c++) acc[a][c]=(f32x4){0.f,0.f,0.f,0.f};
  const int r0=tid>>2;
  const int kcs=(((tid&3)^((r0>>1)&3))<<3);
  const u16* A0 = Wg + (size_t)(o0+r0)*K + kcs;
  const u16* A1 = A0 + (size_t)64*K;
  const u16* B0 = Hin + ((size_t)b*2048 + n0 + r0)*K + kcs;
  const u16* B1 = B0 + (size_t)64*K;
  u16* Aw = As + wid*512;   // wave-uniform LDS base; HW adds lane*16B
  u16* Bw = Bs + wid*512;
  const int sw = (lm>>1)&3;
  const int qs = ((quad^sw)<<3);
  for(int k0=0;k0<K;k0+=32){
    __syncthreads();
    gl16(A0+k0, Aw);  gl16(A1+k0, Aw+2048);
    gl16(B0+k0, Bw);  gl16(B1+k0, Bw+2048);
    __syncthreads();
    bf16x8 af[4], bfr[4];
    #pragma unroll
    for(int mi=0;mi<4;mi++) af[mi]=*(const bf16x8*)(As + ((wr<<6)+(mi<<4)+lm)*32 + qs);
    #pragma unroll
    for(int ni=0;ni<4;ni++) bfr[ni]=*(const bf16x8*)(Bs + ((wc<<6)+(ni<<4)+lm)*32 + qs);
    #pragma unroll
    for(int mi=0;mi<4;mi++)
      #pragma unroll
      for(int ni=0;ni<4;ni++)
        acc[mi][ni]=__builtin_amdgcn_mfma_f32_16x16x32_bf16(af[mi],bfr[ni],acc[mi][ni],0,0,0);
  }
  #pragma unroll
  for(int mi=0;mi<4;mi++){
    const int o = o0 + (wr<<6) + (mi<<4) + (quad<<2);
    float g0=BNS*g[o],  g1v=BNS*g[o+1], g2v=BNS*g[o+2], g3v=BNS*g[o+3];
    float b0=bb[o], b1v=bb[o+1], b2v=bb[o+2], b3v=bb[o+3];
    #pragma unroll
    for(int ni=0;ni<4;ni++){
      const int n = n0 + (wc<<6) + (ni<<4) + lm;
      const size_t pt = (size_t)b*2048 + n;
      f32x4 cc = acc[mi][ni];
      float y0=leaky(cc.x*g0+b0);
      float y1=leaky(cc.y*g1v+b1v);
      float y2=leaky(cc.z*g2v+b2v);
      float y3=leaky(cc.w*g3v+b3v);
      if constexpr(OUT32){
        f32x4 sv={y0,y1,y2,y3};
        *(f32x4*)(Xout + pt*OSTR + o)=sv;
      }
      ushort4 st={f2b(y0),f2b(y1),f2b(y2),f2b(y3)};
      *(ushort4*)(Hc + pt*HCS + hoff + o)=st;
    }
  }
}

// ---------- head: per-point scores = leaky(x5 . Watt^T) ----------
__global__ __launch_bounds__(256) void k_scores(const u16* __restrict__ X5, const float* __restrict__ Watt,
                                                float* __restrict__ S){
  __shared__ __align__(16) f32x4 Wa[1024];
  for(int u=threadIdx.x; u<1024; u+=256){
    f32x4 w; w.x=Watt[u]; w.y=Watt[1024+u]; w.z=Watt[2048+u]; w.w=Watt[3072+u];
    Wa[u]=w;
  }
  __syncthreads();
  const int i = blockIdx.x*256 + threadIdx.x;
  const u16* xr = X5 + (size_t)i*1024;
  f32x4 a={0.f,0.f,0.f,0.f};
  for(int k0=0;k0<1024;k0+=8){
    uint4 hv=*(const uint4*)(xr+k0);
    float hh[8];
    hh[0]=b2f(hv.x&0xffff); hh[1]=b2f(hv.x>>16);
    hh[2]=b2f(hv.y&0xffff); hh[3]=b2f(hv.y>>16);
    hh[4]=b2f(hv.z&0xffff); hh[5]=b2f(hv.z>>16);
    hh[6]=b2f(hv.w&0xffff); hh[7]=b2f(hv.w>>16);
    #pragma unroll
    for(int kk=0;kk<8;kk++){
      f32x4 w=Wa[k0+kk];
      a.x+=hh[kk]*w.x; a.y+=hh[kk]*w.y; a.z+=hh[kk]*w.z; a.w+=hh[kk]*w.w;
    }
  }
  f32x4 sv={leaky(a.x),leaky(a.y),leaky(a.z),leaky(a.w)};
  ((f32x4*)S)[i]=sv;
}

// ---------- head: att[b,h,e] = sum_n x5[b,n,e]*S[b,n,h] (atomic partials) ----------
__global__ __launch_bounds__(256) void k_att(const u16* __restrict__ X5, const float* __restrict__ S,
                                             float* __restrict__ att){
  __shared__ __align__(16) f32x4 Sh[256];
  const int b=blockIdx.z, e=(blockIdx.x<<8)+threadIdx.x, nbase=blockIdx.y<<8;
  Sh[threadIdx.x]=((const f32x4*)S)[(((size_t)b)<<11)+nbase+threadIdx.x];
  __syncthreads();
  f32x4 a={0.f,0.f,0.f,0.f};
  const u16* xp = X5 + ((((size_t)b)<<11)+nbase)*1024 + e;
  for(int nn=0;nn<256;nn++){
    float xv=b2f(xp[(size_t)nn*1024]);
    f32x4 s=Sh[nn];
    a.x+=xv*s.x; a.y+=xv*s.y; a.z+=xv*s.z; a.w+=xv*s.w;
  }
  float* ab = att + (((size_t)b)<<12) + e;
  atomicAdd(ab,      a.x); atomicAdd(ab+1024, a.y);
  atomicAdd(ab+2048, a.z); atomicAdd(ab+3072, a.w);
}

// ---------- head: layernorm + leaky ----------
__global__ __launch_bounds__(256) void k_ln(const float* __restrict__ att, const float* __restrict__ lg,
                                            const float* __restrict__ lb, float* __restrict__ L){
  const int b=blockIdx.x, t=threadIdx.x;
  const float* a = att + (((size_t)b)<<12);
  float s=0.f, sq=0.f;
  for(int u=t;u<4096;u+=256){ float x=a[u]; s+=x; sq+=x*x; }
  s=wredsum(s); sq=wredsum(sq);
  __shared__ float rs[4], rq[4];
  const int wid=t>>6, lane=t&63;
  if(lane==0){ rs[wid]=s; rq[wid]=sq; }
  __syncthreads();
  s=rs[0]+rs[1]+rs[2]+rs[3];
  sq=rq[0]+rq[1]+rq[2]+rq[3];
  const float mean=s*(1.f/4096.f);
  const float var=sq*(1.f/4096.f)-mean*mean;
  const float rstd=rsqrtf(var+1e-5f);
  float* Lb = L + (((size_t)b)<<12);
  for(int u=t;u<4096;u+=256){
    float x=(a[u]-mean)*rstd*lg[u]+lb[u];
    Lb[u]=leaky(x);
  }
}

// ---------- head: fc1 weight-stationary (reads Wl1 once, loops batches) ----------
__global__ __launch_bounds__(256) void k_fcB(const float* __restrict__ Xin, const float* __restrict__ Wg,
                                             const float* __restrict__ bias, const float* __restrict__ g,
                                             const float* __restrict__ bb, float* __restrict__ out){
  const int o = blockIdx.x*4 + (threadIdx.x>>6);   // 512 outputs, 128 blocks
  const int lane = threadIdx.x&63;
  const float* wr = Wg + (size_t)o*4096 + lane*64;
  f32x4 wv[16];
  #pragma unroll
  for(int c=0;c<16;c++) wv[c]=*(const f32x4*)(wr+c*4);
  const float gg=BNS*g[o], bbv=bb[o], bi=bias[o];
  for(int b=0;b<16;b++){
    const float* xr = Xin + (size_t)b*4096 + lane*64;
    float s=0.f;
    #pragma unroll
    for(int c=0;c<16;c++){
      f32x4 xv=*(const f32x4*)(xr+c*4);
      s += xv.x*wv[c].x + xv.y*wv[c].y + xv.z*wv[c].z + xv.w*wv[c].w;
    }
    s = wredsum(s);
    if(lane==0) out[(size_t)b*512+o] = leaky((s+bi)*gg+bbv);
  }
}

// ---------- head: FC (wave-per-output), all-f32 ----------
template<int IN,int OUT,int MODE>
__global__ __launch_bounds__(256) void k_fc(const float* __restrict__ Xin, const float* __restrict__ Wg,
                                            const float* __restrict__ bias, const float* __restrict__ g,
                                            const float* __restrict__ bb, float* __restrict__ out){
  const int gw=(blockIdx.x<<2)+(threadIdx.x>>6);
  const int lane=threadIdx.x&63;
  const int o=gw%OUT, b=gw/OUT;
  constexpr int CHL=IN/64;
  const float* xr = Xin + (size_t)b*IN + lane*CHL;
  const float* wr = Wg  + (size_t)o*IN + lane*CHL;
  float a=0.f;
  #pragma unroll
  for(int c=0;c<CHL;c+=4){
    f32x4 wv=*(const f32x4*)(wr+c);
    f32x4 xv=*(const f32x4*)(xr+c);
    a+=xv.x*wv.x + xv.y*wv.y + xv.z*wv.z + xv.w*wv.w;
  }
  a=wredsum(a);
  if(lane==0){
    float y=a+bias[o];
    if constexpr(MODE<2){
      y=leaky(y*(BNS*g[o])+bb[o]);
    }
    out[(size_t)b*OUT+o]=y;
  }
}

extern "C" void kernel_launch(void* const* d_in, const int* in_sizes, int n_in,
                              void* d_out, int out_size, void* d_ws, size_t ws_size,
                              hipStream_t stream){
  const float* x  =(const float*)d_in[0];
  const float* W1 =(const float*)d_in[1];
  const float* g1 =(const float*)d_in[2];
  const float* b1 =(const float*)d_in[3];
  const float* W2 =(const float*)d_in[4];
  const float* g2 =(const float*)d_in[5];
  const float* b2 =(const float*)d_in[6];
  const float* W3 =(const float*)d_in[7];
  const float* g3 =(const float*)d_in[8];
  const float* b3 =(const float*)d_in[9];
  const float* W4 =(const float*)d_in[10];
  const float* g4 =(const float*)d_in[11];
  const float* b4 =(const float*)d_in[12];
  const float* W5 =(const float*)d_in[13];
  const float* g5 =(const float*)d_in[14];
  const float* b5 =(const float*)d_in[15];
  const float* Watt=(const float*)d_in[16];
  const float* lng=(const float*)d_in[17];
  const float* lnb=(const float*)d_in[18];
  const float* Wl1=(const float*)d_in[19];
  const float* bl1=(const float*)d_in[20];
  const float* g6 =(const float*)d_in[21];
  const float* b6 =(const float*)d_in[22];
  const float* Wl2=(const float*)d_in[23];
  const float* bl2=(const float*)d_in[24];
  const float* g7 =(const float*)d_in[25];
  const float* b7 =(const float*)d_in[26];
  const float* Wl3=(const float*)d_in[27];
  const float* bl3=(const float*)d_in[28];
  char* ws=(char*)d_ws;
  if(ws_size < (size_t)173367296) return;
  float* X0 =(float*)(ws+0);
  float* X1 =(float*)(ws+524288);
  float* X2 =(float*)(ws+8912896);
  float* X3 =(float*)(ws+17301504);
  u16*   H  =(u16*)  (ws+34078720);
  u16*   Hc =(u16*)  (ws+50855936);
  u16*   XP =(u16*)  (ws+84410368);
  u16*   XA1=(u16*)  (ws+84410368);
  u16*   XB1=(u16*)  (ws+86507520);
  float* S  =(float*)(ws+101187584);    // (4,2048,2048) f32 = 64 MB, reused per group
  u16*   X5 =(u16*)  (ws+101187584);    // overlays S (dead by conv5), 64 MB
  float* xx =(float*)(ws+168296448);
  int*   knn=(int*)  (ws+168427520);
  float* Wp1=(float*)(ws+171048960);
  u16*   Wb3=(u16*)  (ws+171057152);
  u16*   Wb4=(u16*)  (ws+171089920);
  u16*   Wb5=(u16*)  (ws+171220992);
  float* Ssc=(float*)(ws+172269568);
  float* att=(float*)(ws+172793856);
  float* L  =(float*)(ws+173056000);
  float* y1 =(float*)(ws+173318144);
  float* y2 =(float*)(ws+173350912);

  k_prep0 <<<128,256,0,stream>>>(x,X0,XA1,XB1,xx);
  k_packw1<<<1,  256,0,stream>>>(W1,Wp1);
  k_w2bAll<<<2368,256,0,stream>>>(W3,W4,W5,Wb3,Wb4,Wb5);

  // ---- layer 1 (C=3 padded to 4) ----
  for(int g=0;g<4;g++){
    k_pdg<32,32,32><<<dim3(16,16,4),256,0,stream>>>(XB1+(size_t)g*8192*32, XA1+(size_t)g*8192*32, xx+(size_t)g*8192, S);
    k_selG<true><<<2048,256,0,stream>>>(S, knn+(size_t)g*8192*20);
  }
  k_attn<4,32,4><<<512,256,0,stream>>>(X0,knn,H);
  k_vconv<32>   <<<512,256,0,stream>>>(H,Wp1,g1,b1,X1,Hc,0);

  // ---- layer 2 (C=64) ----
  k_split<64>  <<<512,256,0,stream>>>(X1,XP,xx);
  for(int g=0;g<4;g++){
    k_pdg<192,64,128><<<dim3(16,16,4),256,0,stream>>>(XP+(size_t)g*8192*128, XP+(size_t)g*8192*128, xx+(size_t)g*8192, S);
    k_selG<false><<<2048,256,0,stream>>>(S, knn+(size_t)g*8192*20);
  }
  k_attn<64,128,4><<<512,256,0,stream>>>(X1,knn,H);
  k_vconv<128>    <<<512,256,0,stream>>>(H,W2,g2,b2,X2,Hc,64);

  // ---- layer 3 (C=64 -> O=128) ----
  k_split<64>  <<<512,256,0,stream>>>(X2,XP,xx);
  for(int g=0;g<4;g++){
    k_pdg<192,64,128><<<dim3(16,16,4),256,0,stream>>>(XP+(size_t)g*8192*128, XP+(size_t)g*8192*128, xx+(size_t)g*8192, S);
    k_selG<false><<<2048,256,0,stream>>>(S, knn+(size_t)g*8192*20);
  }
  k_attn<64,128,4><<<512,256,0,stream>>>(X2,knn,H);
  k_cmfma<128,128,true,512><<<dim3(16,1,16),256,0,stream>>>(Wb3,H,g3,b3,X3,Hc,128);

  // ---- layer 4 (C=128 -> O=256) ----
  k_split<128> <<<512,256,0,stream>>>(X3,XP,xx);
  for(int g=0;g<4;g++){
    k_pdg<384,128,256><<<dim3(16,16,4),256,0,stream>>>(XP+(size_t)g*8192*256, XP+(size_t)g*8192*256, xx+(size_t)g*8192, S);
    k_selG<false><<<2048,256,0,stream>>>(S, knn+(size_t)g*8192*20);
  }
  k_attn<128,256,8><<<1024,256,0,stream>>>(X3,knn,H);
  k_cmfma<256,1,false,512><<<dim3(16,2,16),256,0,stream>>>(Wb4,H,g4,b4,nullptr,Hc,256);

  // ---- conv5 (512 -> 1024) ----
  k_cmfma<512,1,false,1024><<<dim3(16,8,16),256,0,stream>>>(Wb5,Hc,g5,b5,nullptr,X5,0);

  // ---- head ----
  k_scores<<<128,256,0,stream>>>(X5,Watt,Ssc);
  hipMemsetAsync(att,0,16*4096*4,stream);
  k_att   <<<dim3(4,8,16),256,0,stream>>>(X5,Ssc,att);
  k_ln    <<<16,256,0,stream>>>(att,lng,lnb,L);
  k_fcB   <<<128,256,0,stream>>>(L,Wl1,bl1,g6,b6,y1);
  k_fc<512,256,0> <<<1024,256,0,stream>>>(y1,Wl2,bl2,g7,b7,y2);
  k_fc<256,40,2>  <<<160, 256,0,stream>>>(y2,Wl3,bl3,nullptr,nullptr,(float*)d_out);
}

// Round 11
// 1050.295 us; speedup vs baseline: 1.5227x; 1.1512x over previous
//
#include <hip/hip_runtime.h>

#define DEV __device__ __forceinline__

typedef unsigned short u16;
typedef unsigned int   u32;
typedef unsigned long long u64;
typedef float f32x4 __attribute__((ext_vector_type(4)));
typedef __bf16 bf16x8 __attribute__((ext_vector_type(8)));

static constexpr float BNS = 0.9999950000374997f; // 1/sqrt(1+1e-5)

DEV float b2f(u32 s){ union{u32 i; float f;} c; c.i = s<<16; return c.f; }
DEV u16   f2b(float x){ union{float f; u32 i;} c; c.f=x; u32 r=c.i + 0x7fffu + ((c.i>>16)&1u); return (u16)(r>>16); }
DEV float leaky(float x){ return x>0.f ? x : 0.2f*x; }
DEV float wredsum(float v){
  #pragma unroll
  for(int d=32; d; d>>=1) v += __shfl_xor(v, d);
  return v;
}
DEV void gl16(const void* g, void* l){
  __builtin_amdgcn_global_load_lds((const __attribute__((address_space(1))) u32*)g,
                                   (__attribute__((address_space(3))) u32*)l, 16, 0, 0);
}
// full bitonic sort, descending, 64 lanes, u32 keys
DEV u32 bsort64u(u32 k, int lane){
  #pragma unroll
  for(int kk=2; kk<=64; kk<<=1){
    #pragma unroll
    for(int j=kk>>1; j>0; j>>=1){
      u32 o = __shfl_xor(k, j);
      bool km = ((lane & kk)==0) == ((lane & j)==0);
      k = (km == (k > o)) ? k : o;
    }
  }
  return k;
}

// ---------- fused prep: x(B,3,N) -> X0(B,N,4) + XA1/XB1 split packs + xx ----------
__global__ __launch_bounds__(256) void k_prep0(const float* __restrict__ x, float* __restrict__ X0,
                                               u16* __restrict__ XA1, u16* __restrict__ XB1,
                                               float* __restrict__ xx){
  int i = blockIdx.x*256 + threadIdx.x;          // b*N+n, 32768
  int b = i>>11, n = i&2047;
  const float* xb = x + ((size_t)b*3)*2048 + n;
  float vx=xb[0], vy=xb[2048], vz=xb[4096];
  f32x4 v; v.x=vx; v.y=vy; v.z=vz; v.w=0.f;
  ((f32x4*)X0)[i] = v;
  xx[i] = (vx*vx+vy*vy)+vz*vz;
  u16 h0=f2b(vx),h1=f2b(vy),h2=f2b(vz),h3=0;
  ushort4 hh={h0,h1,h2,h3};
  ushort4 ll={f2b(vx-b2f(h0)),f2b(vy-b2f(h1)),f2b(vz-b2f(h2)),0};
  ushort4 zz={0,0,0,0};
  u16* a = XA1 + (size_t)i*32;
  u16* bp = XB1 + (size_t)i*32;
  *(ushort4*)(a)=hh;  *(ushort4*)(a+4)=ll; *(ushort4*)(a+8)=hh;
  *(ushort4*)(bp)=hh; *(ushort4*)(bp+4)=hh; *(ushort4*)(bp+8)=ll;
  #pragma unroll
  for(int c=12;c<32;c+=4){ *(ushort4*)(a+c)=zz; *(ushort4*)(bp+c)=zz; }
}

// ---------- pack W1 (64,6) f32 -> (64,32) f32 matching padded H1 layout ----------
__global__ __launch_bounds__(256) void k_packw1(const float* __restrict__ W1, float* __restrict__ Wp){
  for(int u=threadIdx.x; u<2048; u+=256){
    int o=u>>5, c=u&31;
    float val=0.f;
    if(c<3)            val = W1[o*6+c];
    else if(c>=4&&c<7) val = W1[o*6+3+(c-4)];
    Wp[u]=val;
  }
}

// ---------- pack all conv weights f32 -> bf16 in one dispatch ----------
__global__ __launch_bounds__(256) void k_w2bAll(const float* __restrict__ W3, const float* __restrict__ W4,
                                                const float* __restrict__ W5, u16* __restrict__ Wb3,
                                                u16* __restrict__ Wb4, u16* __restrict__ Wb5){
  int i = blockIdx.x*256 + threadIdx.x;          // 606208 total
  if(i<16384)       Wb3[i]=f2b(W3[i]);
  else if(i<81920)  Wb4[i-16384]=f2b(W4[i-16384]);
  else if(i<606208) Wb5[i-81920]=f2b(W5[i-81920]);
}

// ---------- split-bf16 pack + fused sqnorm ----------
template<int CP>
__global__ __launch_bounds__(256) void k_split(const float* __restrict__ X, u16* __restrict__ XP,
                                               float* __restrict__ xx){
  const int gi = blockIdx.x*256 + threadIdx.x;   // 4 threads per point
  const int i = gi>>2, part = gi&3;
  constexpr int CH = CP/4;
  const float* xr = X + (size_t)i*CP + part*CH;
  u16* ph = XP + (size_t)i*(2*CP) + part*CH;
  u16* pl = ph + CP;
  f32x4 a4 = {0.f,0.f,0.f,0.f};
  #pragma unroll
  for(int c=0;c<CH;c+=4){
    f32x4 v = *(const f32x4*)(xr+c);
    a4 += v*v;
    u16 h0=f2b(v.x),h1=f2b(v.y),h2=f2b(v.z),h3=f2b(v.w);
    ushort4 hh={h0,h1,h2,h3};
    ushort4 ll={f2b(v.x-b2f(h0)),f2b(v.y-b2f(h1)),f2b(v.z-b2f(h2)),f2b(v.w-b2f(h3))};
    *(ushort4*)(ph+c)=hh; *(ushort4*)(pl+c)=ll;
  }
  float s=(a4.x+a4.y)+(a4.z+a4.w);
  s += __shfl_xor(s,1);
  s += __shfl_xor(s,2);
  if(part==0) xx[i]=s;
}

// ---------- layer-1 pd GEMM (BK=32), stores bf16 p = 2s - xx[col] ----------
__global__ __launch_bounds__(256) void k_pdg32(const u16* __restrict__ Qb, const u16* __restrict__ Cb,
                                               const float* __restrict__ xxg, u16* __restrict__ Sb){
  __shared__ __align__(16) u16 As[128*32];
  __shared__ __align__(16) u16 Bs[128*32];
  const int tid=threadIdx.x, b=blockIdx.z;
  const int n0=blockIdx.x<<7, o0=blockIdx.y<<7;
  const int wid=tid>>6, lane=tid&63, wr=wid>>1, wc=wid&1, lm=lane&15, quad=lane>>4;
  f32x4 acc[4][4];
  #pragma unroll
  for(int a=0;a<4;a++)
    #pragma unroll
    for(int c=0;c<4;c++) acc[a][c]=(f32x4){0.f,0.f,0.f,0.f};
  const int r0=tid>>2;
  const int kcs=(((tid&3)^((r0>>1)&3))<<3);
  const u16* A0 = Qb + ((size_t)b*2048 + n0 + r0)*32 + kcs;
  const u16* A1 = A0 + (size_t)64*32;
  const u16* B0 = Cb + ((size_t)b*2048 + o0 + r0)*32 + kcs;
  const u16* B1 = B0 + (size_t)64*32;
  u16* Aw = As + wid*512;
  u16* Bw = Bs + wid*512;
  const int qs = ((quad^((lm>>1)&3))<<3);
  __syncthreads();
  gl16(A0, Aw);  gl16(A1, Aw+2048);
  gl16(B0, Bw);  gl16(B1, Bw+2048);
  __syncthreads();
  {
    bf16x8 af[4], bfr[4];
    #pragma unroll
    for(int mi=0;mi<4;mi++) af[mi]=*(const bf16x8*)(As + ((wr<<6)+(mi<<4)+lm)*32 + qs);
    #pragma unroll
    for(int ni=0;ni<4;ni++) bfr[ni]=*(const bf16x8*)(Bs + ((wc<<6)+(ni<<4)+lm)*32 + qs);
    #pragma unroll
    for(int mi=0;mi<4;mi++)
      #pragma unroll
      for(int ni=0;ni<4;ni++)
        acc[mi][ni]=__builtin_amdgcn_mfma_f32_16x16x32_bf16(af[mi],bfr[ni],acc[mi][ni],0,0,0);
  }
  float xn[4];
  #pragma unroll
  for(int ni=0;ni<4;ni++) xn[ni] = xxg[(size_t)b*2048 + o0 + (wc<<6)+(ni<<4)+lm];
  #pragma unroll
  for(int mi=0;mi<4;mi++){
    const int qr = n0 + (wr<<6)+(mi<<4)+(quad<<2);
    #pragma unroll
    for(int ni=0;ni<4;ni++){
      const int cd = o0 + (wc<<6)+(ni<<4)+lm;
      f32x4 cc = acc[mi][ni];
      u16* sp = Sb + ((size_t)b*2048 + qr)*2048 + cd;
      sp[0]   = f2b(cc.x+cc.x-xn[ni]);
      sp[2048]= f2b(cc.y+cc.y-xn[ni]);
      sp[4096]= f2b(cc.z+cc.z-xn[ni]);
      sp[6144]= f2b(cc.w+cc.w-xn[ni]);
    }
  }
}

// ---------- pd GEMM BK=64 (layers 2-4); stores bf16 p ----------
template<int KP,int CPM>
__global__ __launch_bounds__(256) void k_pdg64(const u16* __restrict__ Qb, const u16* __restrict__ Cb,
                                               const float* __restrict__ xxg, u16* __restrict__ Sb){
  constexpr int STR = 2*CPM;
  __shared__ __align__(16) u16 As[128*64];
  __shared__ __align__(16) u16 Bs[128*64];
  const int tid=threadIdx.x, b=blockIdx.z;
  const int n0=blockIdx.x<<7, o0=blockIdx.y<<7;
  const int wid=tid>>6, lane=tid&63, wr=wid>>1, wc=wid&1, lm=lane&15, quad=lane>>4;
  f32x4 acc[4][4];
  #pragma unroll
  for(int a=0;a<4;a++)
    #pragma unroll
    for(int c=0;c<4;c++) acc[a][c]=(f32x4){0.f,0.f,0.f,0.f};
  const int r = tid>>3;                       // 0..31
  const int csw = ((tid&7)^(r&7))<<3;         // swizzled source col (u16)
  const u16* A0 = Qb + ((size_t)b*2048 + n0 + r)*STR + csw;
  const u16* B0 = Cb + ((size_t)b*2048 + o0 + r)*STR + csw;
  for(int k0=0;k0<KP;k0+=64){
    const int aoff = (k0<CPM)? k0 : k0-CPM;        // queries: [h,h,l]
    const int boff = (k0<2*CPM)? k0 : k0-2*CPM;    // candidates: [h,l,h]
    __syncthreads();
    #pragma unroll
    for(int cc=0;cc<4;cc++){
      gl16(A0+aoff+(size_t)(cc*32)*STR, As + cc*2048 + wid*512);
      gl16(B0+boff+(size_t)(cc*32)*STR, Bs + cc*2048 + wid*512);
    }
    __syncthreads();
    #pragma unroll
    for(int sub=0;sub<2;sub++){
      const int eff = (((sub<<2)|quad)^(lm&7))<<3;
      bf16x8 af[4], bfr[4];
      #pragma unroll
      for(int mi=0;mi<4;mi++) af[mi]=*(const bf16x8*)(As + ((wr<<6)+(mi<<4)+lm)*64 + eff);
      #pragma unroll
      for(int ni=0;ni<4;ni++) bfr[ni]=*(const bf16x8*)(Bs + ((wc<<6)+(ni<<4)+lm)*64 + eff);
      #pragma unroll
      for(int mi=0;mi<4;mi++)
        #pragma unroll
        for(int ni=0;ni<4;ni++)
          acc[mi][ni]=__builtin_amdgcn_mfma_f32_16x16x32_bf16(af[mi],bfr[ni],acc[mi][ni],0,0,0);
    }
  }
  float xn[4];
  #pragma unroll
  for(int ni=0;ni<4;ni++) xn[ni] = xxg[(size_t)b*2048 + o0 + (wc<<6)+(ni<<4)+lm];
  #pragma unroll
  for(int mi=0;mi<4;mi++){
    const int qr = n0 + (wr<<6)+(mi<<4)+(quad<<2);
    #pragma unroll
    for(int ni=0;ni<4;ni++){
      const int cd = o0 + (wc<<6)+(ni<<4)+lm;
      f32x4 cc = acc[mi][ni];
      u16* sp = Sb + ((size_t)b*2048 + qr)*2048 + cd;
      sp[0]   = f2b(cc.x+cc.x-xn[ni]);
      sp[2048]= f2b(cc.y+cc.y-xn[ni]);
      sp[4096]= f2b(cc.z+cc.z-xn[ni]);
      sp[6144]= f2b(cc.w+cc.w-xn[ni]);
    }
  }
}

// ---------- full-row wave-coop top-20 select, u32 keys, kNN-warm-start prime ----------
template<bool L1>
__global__ __launch_bounds__(256) void k_selG(const u16* __restrict__ Sb, int* __restrict__ knn){
  __shared__ u32 buf[4][320];
  __shared__ u32 cw[4];
  const int w=threadIdx.x>>6, lane=threadIdx.x&63;
  const int row = blockIdx.x*4 + w;      // 0..8191 (4 batches x 2048)
  const int q = row & 2047;
  if(lane==0) cw[w]=0;
  __builtin_amdgcn_wave_barrier();
  __asm__ volatile("s_waitcnt lgkmcnt(0)" ::: "memory");
  const u16* Srow = Sb + (size_t)row*2048;
  // ---- prime: threshold = 20th-best of 20 real candidates ----
  int pc;
  if constexpr(L1) pc = (q + 1 + lane) & 2047;
  else             pc = (lane<20) ? knn[(size_t)row*20+lane] : q;
  u32 praw = Srow[pc];
  u32 pmk = praw ^ ((praw&0x8000u)? 0xFFFFu : 0x8000u);
  u32 pkey = (pmk<<16) | (u32)(2047-pc);
  if(lane>=20) pkey=0;
  pkey = bsort64u(pkey,lane);
  u32 top=0;
  u32 T = __shfl(pkey,19);
  u32 Tmk = T>>16;
  auto flush=[&](){
    __builtin_amdgcn_wave_barrier();
    __asm__ volatile("s_waitcnt lgkmcnt(0)" ::: "memory");
    const int cnt=(int)cw[w];
    __builtin_amdgcn_wave_barrier();
    for(int done=0; done<cnt; done+=64){
      u32 bk = (lane < cnt-done) ? buf[w][done+lane] : 0;
      u32 sb = bsort64u(bk, lane);
      u32 rev = __shfl(sb,(31-lane)&63);
      u32 c2 = (lane<32) ? (top>rev?top:rev) : 0;
      #pragma unroll
      for(int j=16;j>0;j>>=1){
        u32 o = __shfl_xor(c2,j);
        bool km=(lane&j)==0;
        c2 = (km==(c2>o))?c2:o;
      }
      top = (lane<20)?c2:0;
    }
    T = __shfl(top,19);
    Tmk = T>>16;
    if(lane==0) cw[w]=0;
    __builtin_amdgcn_wave_barrier();
    __asm__ volatile("s_waitcnt lgkmcnt(0)" ::: "memory");
  };
  #pragma unroll 1
  for(int g=0;g<8;++g){
    const int c0=g*256 + (lane<<2);
    ushort4 s4=*(const ushort4*)(Srow+c0);
    u32 mk0 = (u32)s4.x ^ ((s4.x&0x8000u)?0xFFFFu:0x8000u);
    u32 mk1 = (u32)s4.y ^ ((s4.y&0x8000u)?0xFFFFu:0x8000u);
    u32 mk2 = (u32)s4.z ^ ((s4.z&0x8000u)?0xFFFFu:0x8000u);
    u32 mk3 = (u32)s4.w ^ ((s4.w&0x8000u)?0xFFFFu:0x8000u);
    u32 mmax = max(max(mk0,mk1),max(mk2,mk3));
    if(__ballot(mmax >= Tmk)){
      u32 mks[4]={mk0,mk1,mk2,mk3};
      #pragma unroll
      for(int e=0;e<4;e++){
        const int col=c0+e;
        u32 key=(mks[e]<<16)|(u32)(2047-col);
        if(key>=T && col!=q){
          u32 pos=atomicAdd(&cw[w],1u);
          buf[w][pos]=key;
        }
      }
      __builtin_amdgcn_wave_barrier();
      __asm__ volatile("s_waitcnt lgkmcnt(0)" ::: "memory");
      const int c=(int)cw[w];
      if(c>64) flush();
    }
  }
  flush();
  if(lane<20) knn[(size_t)row*20+lane]=2047-(int)(top&0xFFFFu);
}

// ---------- attention (channel-split, TPP threads/point) ----------
template<int CP,int HS,int TPP>
__global__ __launch_bounds__(256) void k_attn(const float* __restrict__ X, const int* __restrict__ knn,
                                              u16* __restrict__ H){
  constexpr int CH = CP/TPP;
  const int gi = blockIdx.x*256 + threadIdx.x;
  const int i = gi/TPP, t = gi%TPP;
  const float* Xb = X + (((size_t)(i>>11))<<11)*CP;
  const float* q  = X + (size_t)i*CP + t*CH;
  int nb[20];
  { const int* kp = knn + (size_t)i*20;
    #pragma unroll
    for(int j=0;j<20;j++) nb[j]=kp[j]; }
  float qc[CH];
  if constexpr(CH>=4){
    #pragma unroll
    for(int c=0;c<CH;c+=4){
      f32x4 vv = *(const f32x4*)(q+c);
      qc[c]=vv.x; qc[c+1]=vv.y; qc[c+2]=vv.z; qc[c+3]=vv.w;
    }
  } else {
    qc[0]=q[0];
  }
  float s[20];
  #pragma unroll
  for(int j=0;j<20;j++){
    const float* kr = Xb + (size_t)nb[j]*CP + t*CH;
    float a=0.f;
    if constexpr(CH>=4){
      #pragma unroll
      for(int c=0;c<CH;c+=4){
        f32x4 kv = *(const f32x4*)(kr+c);
        a += kv.x*qc[c] + kv.y*qc[c+1] + kv.z*qc[c+2] + kv.w*qc[c+3];
      }
    } else {
      a = qc[0]*kr[0];
    }
    s[j]=a;
  }
  #pragma unroll
  for(int j=0;j<20;j++){
    #pragma unroll
    for(int d=1;d<TPP;d<<=1) s[j] += __shfl_xor(s[j], d);
  }
  float mx=s[0];
  #pragma unroll
  for(int j=1;j<20;j++) mx=fmaxf(mx,s[j]);
  float sum=0.f;
  #pragma unroll
  for(int j=0;j<20;j++){ s[j]=__expf(s[j]-mx); sum+=s[j]; }
  float inv=1.f/sum;
  #pragma unroll
  for(int j=0;j<20;j++) s[j]*=inv;
  float f[CH];
  #pragma unroll
  for(int c=0;c<CH;c++) f[c]=0.f;
  #pragma unroll
  for(int j=0;j<20;j++){
    const float* kr = Xb + (size_t)nb[j]*CP + t*CH;
    const float w = s[j];
    if constexpr(CH>=4){
      #pragma unroll
      for(int c=0;c<CH;c+=4){
        f32x4 kv = *(const f32x4*)(kr+c);
        f[c]+=w*kv.x; f[c+1]+=w*kv.y; f[c+2]+=w*kv.z; f[c+3]+=w*kv.w;
      }
    } else {
      f[0]+=w*kr[0];
    }
  }
  u16* ho = H + (size_t)i*HS;
  if constexpr(CH>=4){
    #pragma unroll
    for(int c=0;c<CH;c+=4){
      ushort4 qsv = {f2b(qc[c]),f2b(qc[c+1]),f2b(qc[c+2]),f2b(qc[c+3])};
      *(ushort4*)(ho + t*CH + c) = qsv;
      ushort4 fs = {f2b(f[c]-qc[c]),f2b(f[c+1]-qc[c+1]),f2b(f[c+2]-qc[c+2]),f2b(f[c+3]-qc[c+3])};
      *(ushort4*)(ho + CP + t*CH + c) = fs;
    }
  } else {
    ho[t]      = f2b(qc[0]);
    ho[CP+t]   = f2b(f[0]-qc[0]);
  }
  if constexpr(HS > 2*CP){
    ushort4 zz={0,0,0,0};
    *(ushort4*)(ho + 2*CP + t*4) = zz;
    if(t < (HS-2*CP-4*TPP)/4) *(ushort4*)(ho + 2*CP + 4*TPP + t*4) = zz;
  }
}

// ---------- vector conv (O=64) ----------
template<int K>
__global__ __launch_bounds__(256) void k_vconv(const u16* __restrict__ H, const float* __restrict__ Wg,
                                               const float* __restrict__ g, const float* __restrict__ bb,
                                               float* __restrict__ Xout, u16* __restrict__ Hc, int hoff){
  __shared__ __align__(16) float Ws[K*64];   // [k][o]
  for(int u=threadIdx.x; u<K*64; u+=256){
    int o=u&63, kk=u>>6;
    Ws[u]=Wg[o*K+kk];
  }
  __syncthreads();
  const int gi = blockIdx.x*256 + threadIdx.x;
  const int i = gi>>2, oc = gi&3;
  const u16* hr = H + (size_t)i*K;
  float acc[16];
  #pragma unroll
  for(int o=0;o<16;o++) acc[o]=0.f;
  for(int k0=0;k0<K;k0+=8){
    uint4 hv = *(const uint4*)(hr+k0);
    float hh[8];
    hh[0]=b2f(hv.x&0xffff); hh[1]=b2f(hv.x>>16);
    hh[2]=b2f(hv.y&0xffff); hh[3]=b2f(hv.y>>16);
    hh[4]=b2f(hv.z&0xffff); hh[5]=b2f(hv.z>>16);
    hh[6]=b2f(hv.w&0xffff); hh[7]=b2f(hv.w>>16);
    #pragma unroll
    for(int kk=0;kk<8;kk++){
      const f32x4* wr = (const f32x4*)(Ws + (k0+kk)*64 + oc*16);
      #pragma unroll
      for(int o4=0;o4<4;o4++){
        f32x4 w = wr[o4];
        acc[o4*4]  +=hh[kk]*w.x; acc[o4*4+1]+=hh[kk]*w.y;
        acc[o4*4+2]+=hh[kk]*w.z; acc[o4*4+3]+=hh[kk]*w.w;
      }
    }
  }
  const int ob = oc*16;
  #pragma unroll
  for(int o=0;o<16;o++) acc[o]=leaky(acc[o]*(BNS*g[ob+o])+bb[ob+o]);
  float* xo = Xout + (size_t)i*64 + ob;
  #pragma unroll
  for(int o=0;o<16;o+=4){ f32x4 sv={acc[o],acc[o+1],acc[o+2],acc[o+3]}; *(f32x4*)(xo+o)=sv; }
  u16* hc = Hc + (size_t)i*512 + hoff + ob;
  #pragma unroll
  for(int o=0;o<16;o+=4){ ushort4 st={f2b(acc[o]),f2b(acc[o+1]),f2b(acc[o+2]),f2b(acc[o+3])}; *(ushort4*)(hc+o)=st; }
}

// ---------- MFMA conv BK=64 (XOR-swizzled LDS) ----------
template<int K,int OSTR,bool OUT32,int HCS>
__global__ __launch_bounds__(256) void k_cmfma(const u16* __restrict__ Wg, const u16* __restrict__ Hin,
                                               const float* __restrict__ g, const float* __restrict__ bb,
                                               float* __restrict__ Xout, u16* __restrict__ Hc, int hoff){
  __shared__ __align__(16) u16 As[128*64];
  __shared__ __align__(16) u16 Bs[128*64];
  const int tid=threadIdx.x, b=blockIdx.z;
  const int n0=blockIdx.x<<7, o0=blockIdx.y<<7;
  const int wid=tid>>6, lane=tid&63, wr=wid>>1, wc=wid&1, lm=lane&15, quad=lane>>4;
  f32x4 acc[4][4];
  #pragma unroll
  for(int a=0;a<4;a++)
    #pragma unroll
    for(int c=0;c<4;c++) acc[a][c]=(f32x4){0.f,0.f,0.f,0.f};
  const int r = tid>>3;
  const int csw = ((tid&7)^(r&7))<<3;
  const u16* A0 = Wg + (size_t)(o0+r)*K + csw;
  const u16* B0 = Hin + ((size_t)b*2048 + n0 + r)*K + csw;
  for(int k0=0;k0<K;k0+=64){
    __syncthreads();
    #pragma unroll
    for(int cc=0;cc<4;cc++){
      gl16(A0+k0+(size_t)(cc*32)*K, As + cc*2048 + wid*512);
      gl16(B0+k0+(size_t)(cc*32)*K, Bs + cc*2048 + wid*512);
    }
    __syncthreads();
    #pragma unroll
    for(int sub=0;sub<2;sub++){
      const int eff = (((sub<<2)|quad)^(lm&7))<<3;
      bf16x8 af[4], bfr[4];
      #pragma unroll
      for(int mi=0;mi<4;mi++) af[mi]=*(const bf16x8*)(As + ((wr<<6)+(mi<<4)+lm)*64 + eff);
      #pragma unroll
      for(int ni=0;ni<4;ni++) bfr[ni]=*(const bf16x8*)(Bs + ((wc<<6)+(ni<<4)+lm)*64 + eff);
      #pragma unroll
      for(int mi=0;mi<4;mi++)
        #pragma unroll
        for(int ni=0;ni<4;ni++)
          acc[mi][ni]=__builtin_amdgcn_mfma_f32_16x16x32_bf16(af[mi],bfr[ni],acc[mi][ni],0,0,0);
    }
  }
  #pragma unroll
  for(int mi=0;mi<4;mi++){
    const int o = o0 + (wr<<6) + (mi<<4) + (quad<<2);
    float g0=BNS*g[o],  g1v=BNS*g[o+1], g2v=BNS*g[o+2], g3v=BNS*g[o+3];
    float b0=bb[o], b1v=bb[o+1], b2v=bb[o+2], b3v=bb[o+3];
    #pragma unroll
    for(int ni=0;ni<4;ni++){
      const int n = n0 + (wc<<6) + (ni<<4) + lm;
      const size_t pt = (size_t)b*2048 + n;
      f32x4 cc = acc[mi][ni];
      float y0=leaky(cc.x*g0+b0);
      float y1=leaky(cc.y*g1v+b1v);
      float y2=leaky(cc.z*g2v+b2v);
      float y3=leaky(cc.w*g3v+b3v);
      if constexpr(OUT32){
        f32x4 sv={y0,y1,y2,y3};
        *(f32x4*)(Xout + pt*OSTR + o)=sv;
      }
      ushort4 st={f2b(y0),f2b(y1),f2b(y2),f2b(y3)};
      *(ushort4*)(Hc + pt*HCS + hoff + o)=st;
    }
  }
}

// ---------- head: per-point scores = leaky(x5 . Watt^T) ----------
__global__ __launch_bounds__(256) void k_scores(const u16* __restrict__ X5, const float* __restrict__ Watt,
                                                float* __restrict__ S){
  __shared__ __align__(16) f32x4 Wa[1024];
  for(int u=threadIdx.x; u<1024; u+=256){
    f32x4 w; w.x=Watt[u]; w.y=Watt[1024+u]; w.z=Watt[2048+u]; w.w=Watt[3072+u];
    Wa[u]=w;
  }
  __syncthreads();
  const int i = blockIdx.x*256 + threadIdx.x;
  const u16* xr = X5 + (size_t)i*1024;
  f32x4 a={0.f,0.f,0.f,0.f};
  for(int k0=0;k0<1024;k0+=8){
    uint4 hv=*(const uint4*)(xr+k0);
    float hh[8];
    hh[0]=b2f(hv.x&0xffff); hh[1]=b2f(hv.x>>16);
    hh[2]=b2f(hv.y&0xffff); hh[3]=b2f(hv.y>>16);
    hh[4]=b2f(hv.z&0xffff); hh[5]=b2f(hv.z>>16);
    hh[6]=b2f(hv.w&0xffff); hh[7]=b2f(hv.w>>16);
    #pragma unroll
    for(int kk=0;kk<8;kk++){
      f32x4 w=Wa[k0+kk];
      a.x+=hh[kk]*w.x; a.y+=hh[kk]*w.y; a.z+=hh[kk]*w.z; a.w+=hh[kk]*w.w;
    }
  }
  f32x4 sv={leaky(a.x),leaky(a.y),leaky(a.z),leaky(a.w)};
  ((f32x4*)S)[i]=sv;
}

// ---------- head: att[b,h,e] = sum_n x5[b,n,e]*S[b,n,h] (atomic partials) ----------
__global__ __launch_bounds__(256) void k_att(const u16* __restrict__ X5, const float* __restrict__ S,
                                             float* __restrict__ att){
  __shared__ __align__(16) f32x4 Sh[256];
  const int b=blockIdx.z, e=(blockIdx.x<<8)+threadIdx.x, nbase=blockIdx.y<<8;
  Sh[threadIdx.x]=((const f32x4*)S)[(((size_t)b)<<11)+nbase+threadIdx.x];
  __syncthreads();
  f32x4 a={0.f,0.f,0.f,0.f};
  const u16* xp = X5 + ((((size_t)b)<<11)+nbase)*1024 + e;
  for(int nn=0;nn<256;nn++){
    float xv=b2f(xp[(size_t)nn*1024]);
    f32x4 s=Sh[nn];
    a.x+=xv*s.x; a.y+=xv*s.y; a.z+=xv*s.z; a.w+=xv*s.w;
  }
  float* ab = att + (((size_t)b)<<12) + e;
  atomicAdd(ab,      a.x); atomicAdd(ab+1024, a.y);
  atomicAdd(ab+2048, a.z); atomicAdd(ab+3072, a.w);
}

// ---------- head: layernorm + leaky ----------
__global__ __launch_bounds__(256) void k_ln(const float* __restrict__ att, const float* __restrict__ lg,
                                            const float* __restrict__ lb, float* __restrict__ L){
  const int b=blockIdx.x, t=threadIdx.x;
  const float* a = att + (((size_t)b)<<12);
  float s=0.f, sq=0.f;
  for(int u=t;u<4096;u+=256){ float x=a[u]; s+=x; sq+=x*x; }
  s=wredsum(s); sq=wredsum(sq);
  __shared__ float rs[4], rq[4];
  const int wid=t>>6, lane=t&63;
  if(lane==0){ rs[wid]=s; rq[wid]=sq; }
  __syncthreads();
  s=rs[0]+rs[1]+rs[2]+rs[3];
  sq=rq[0]+rq[1]+rq[2]+rq[3];
  const float mean=s*(1.f/4096.f);
  const float var=sq*(1.f/4096.f)-mean*mean;
  const float rstd=rsqrtf(var+1e-5f);
  float* Lb = L + (((size_t)b)<<12);
  for(int u=t;u<4096;u+=256){
    float x=(a[u]-mean)*rstd*lg[u]+lb[u];
    Lb[u]=leaky(x);
  }
}

// ---------- head: fc1 weight-stationary ----------
__global__ __launch_bounds__(256) void k_fcB(const float* __restrict__ Xin, const float* __restrict__ Wg,
                                             const float* __restrict__ bias, const float* __restrict__ g,
                                             const float* __restrict__ bb, float* __restrict__ out){
  const int o = blockIdx.x*4 + (threadIdx.x>>6);   // 512 outputs, 128 blocks
  const int lane = threadIdx.x&63;
  const float* wr = Wg + (size_t)o*4096 + lane*64;
  f32x4 wv[16];
  #pragma unroll
  for(int c=0;c<16;c++) wv[c]=*(const f32x4*)(wr+c*4);
  const float gg=BNS*g[o], bbv=bb[o], bi=bias[o];
  for(int b=0;b<16;b++){
    const float* xr = Xin + (size_t)b*4096 + lane*64;
    float s=0.f;
    #pragma unroll
    for(int c=0;c<16;c++){
      f32x4 xv=*(const f32x4*)(xr+c*4);
      s += xv.x*wv[c].x + xv.y*wv[c].y + xv.z*wv[c].z + xv.w*wv[c].w;
    }
    s = wredsum(s);
    if(lane==0) out[(size_t)b*512+o] = leaky((s+bi)*gg+bbv);
  }
}

// ---------- head: FC (wave-per-output), all-f32 ----------
template<int IN,int OUT,int MODE>
__global__ __launch_bounds__(256) void k_fc(const float* __restrict__ Xin, const float* __restrict__ Wg,
                                            const float* __restrict__ bias, const float* __restrict__ g,
                                            const float* __restrict__ bb, float* __restrict__ out){
  const int gw=(blockIdx.x<<2)+(threadIdx.x>>6);
  const int lane=threadIdx.x&63;
  const int o=gw%OUT, b=gw/OUT;
  constexpr int CHL=IN/64;
  const float* xr = Xin + (size_t)b*IN + lane*CHL;
  const float* wr = Wg  + (size_t)o*IN + lane*CHL;
  float a=0.f;
  #pragma unroll
  for(int c=0;c<CHL;c+=4){
    f32x4 wv=*(const f32x4*)(wr+c);
    f32x4 xv=*(const f32x4*)(xr+c);
    a+=xv.x*wv.x + xv.y*wv.y + xv.z*wv.z + xv.w*wv.w;
  }
  a=wredsum(a);
  if(lane==0){
    float y=a+bias[o];
    if constexpr(MODE<2){
      y=leaky(y*(BNS*g[o])+bb[o]);
    }
    out[(size_t)b*OUT+o]=y;
  }
}

extern "C" void kernel_launch(void* const* d_in, const int* in_sizes, int n_in,
                              void* d_out, int out_size, void* d_ws, size_t ws_size,
                              hipStream_t stream){
  const float* x  =(const float*)d_in[0];
  const float* W1 =(const float*)d_in[1];
  const float* g1 =(const float*)d_in[2];
  const float* b1 =(const float*)d_in[3];
  const float* W2 =(const float*)d_in[4];
  const float* g2 =(const float*)d_in[5];
  const float* b2 =(const float*)d_in[6];
  const float* W3 =(const float*)d_in[7];
  const float* g3 =(const float*)d_in[8];
  const float* b3 =(const float*)d_in[9];
  const float* W4 =(const float*)d_in[10];
  const float* g4 =(const float*)d_in[11];
  const float* b4 =(const float*)d_in[12];
  const float* W5 =(const float*)d_in[13];
  const float* g5 =(const float*)d_in[14];
  const float* b5 =(const float*)d_in[15];
  const float* Watt=(const float*)d_in[16];
  const float* lng=(const float*)d_in[17];
  const float* lnb=(const float*)d_in[18];
  const float* Wl1=(const float*)d_in[19];
  const float* bl1=(const float*)d_in[20];
  const float* g6 =(const float*)d_in[21];
  const float* b6 =(const float*)d_in[22];
  const float* Wl2=(const float*)d_in[23];
  const float* bl2=(const float*)d_in[24];
  const float* g7 =(const float*)d_in[25];
  const float* b7 =(const float*)d_in[26];
  const float* Wl3=(const float*)d_in[27];
  const float* bl3=(const float*)d_in[28];
  char* ws=(char*)d_ws;
  if(ws_size < (size_t)173367296) return;
  float* X0 =(float*)(ws+0);
  float* X1 =(float*)(ws+524288);
  float* X2 =(float*)(ws+8912896);
  float* X3 =(float*)(ws+17301504);
  u16*   H  =(u16*)  (ws+34078720);
  u16*   Hc =(u16*)  (ws+50855936);
  u16*   XP =(u16*)  (ws+84410368);
  u16*   XA1=(u16*)  (ws+84410368);
  u16*   XB1=(u16*)  (ws+86507520);
  u16*   S  =(u16*)  (ws+101187584);    // (4,2048,2048) bf16 = 32 MB, reused per group
  u16*   X5 =(u16*)  (ws+101187584);    // overlays S region (dead by conv5), 64 MB
  float* xx =(float*)(ws+168296448);
  int*   knn=(int*)  (ws+168427520);
  float* Wp1=(float*)(ws+171048960);
  u16*   Wb3=(u16*)  (ws+171057152);
  u16*   Wb4=(u16*)  (ws+171089920);
  u16*   Wb5=(u16*)  (ws+171220992);
  float* Ssc=(float*)(ws+172269568);
  float* att=(float*)(ws+172793856);
  float* L  =(float*)(ws+173056000);
  float* y1 =(float*)(ws+173318144);
  float* y2 =(float*)(ws+173350912);

  k_prep0 <<<128,256,0,stream>>>(x,X0,XA1,XB1,xx);
  k_packw1<<<1,  256,0,stream>>>(W1,Wp1);
  k_w2bAll<<<2368,256,0,stream>>>(W3,W4,W5,Wb3,Wb4,Wb5);

  // ---- layer 1 (C=3 padded to 4) ----
  for(int g=0;g<4;g++){
    k_pdg32<<<dim3(16,16,4),256,0,stream>>>(XB1+(size_t)g*8192*32, XA1+(size_t)g*8192*32, xx+(size_t)g*8192, S);
    k_selG<true><<<2048,256,0,stream>>>(S, knn+(size_t)g*8192*20);
  }
  k_attn<4,32,4><<<512,256,0,stream>>>(X0,knn,H);
  k_vconv<32>   <<<512,256,0,stream>>>(H,Wp1,g1,b1,X1,Hc,0);

  // ---- layer 2 (C=64) ----
  k_split<64>  <<<512,256,0,stream>>>(X1,XP,xx);
  for(int g=0;g<4;g++){
    k_pdg64<192,64><<<dim3(16,16,4),256,0,stream>>>(XP+(size_t)g*8192*128, XP+(size_t)g*8192*128, xx+(size_t)g*8192, S);
    k_selG<false><<<2048,256,0,stream>>>(S, knn+(size_t)g*8192*20);
  }
  k_attn<64,128,4><<<512,256,0,stream>>>(X1,knn,H);
  k_vconv<128>    <<<512,256,0,stream>>>(H,W2,g2,b2,X2,Hc,64);

  // ---- layer 3 (C=64 -> O=128) ----
  k_split<64>  <<<512,256,0,stream>>>(X2,XP,xx);
  for(int g=0;g<4;g++){
    k_pdg64<192,64><<<dim3(16,16,4),256,0,stream>>>(XP+(size_t)g*8192*128, XP+(size_t)g*8192*128, xx+(size_t)g*8192, S);
    k_selG<false><<<2048,256,0,stream>>>(S, knn+(size_t)g*8192*20);
  }
  k_attn<64,128,4><<<512,256,0,stream>>>(X2,knn,H);
  k_cmfma<128,128,true,512><<<dim3(16,1,16),256,0,stream>>>(Wb3,H,g3,b3,X3,Hc,128);

  // ---- layer 4 (C=128 -> O=256) ----
  k_split<128> <<<512,256,0,stream>>>(X3,XP,xx);
  for(int g=0;g<4;g++){
    k_pdg64<384,128><<<dim3(16,16,4),256,0,stream>>>(XP+(size_t)g*8192*256, XP+(size_t)g*8192*256, xx+(size_t)g*8192, S);
    k_selG<false><<<2048,256,0,stream>>>(S, knn+(size_t)g*8192*20);
  }
  k_attn<128,256,8><<<1024,256,0,stream>>>(X3,knn,H);
  k_cmfma<256,1,false,512><<<dim3(16,2,16),256,0,stream>>>(Wb4,H,g4,b4,nullptr,Hc,256);

  // ---- conv5 (512 -> 1024) ----
  k_cmfma<512,1,false,1024><<<dim3(16,8,16),256,0,stream>>>(Wb5,Hc,g5,b5,nullptr,X5,0);

  // ---- head ----
  k_scores<<<128,256,0,stream>>>(X5,Watt,Ssc);
  hipMemsetAsync(att,0,16*4096*4,stream);
  k_att   <<<dim3(4,8,16),256,0,stream>>>(X5,Ssc,att);
  k_ln    <<<16,256,0,stream>>>(att,lng,lnb,L);
  k_fcB   <<<128,256,0,stream>>>(L,Wl1,bl1,g6,b6,y1);
  k_fc<512,256,0> <<<1024,256,0,stream>>>(y1,Wl2,bl2,g7,b7,y2);
  k_fc<256,40,2>  <<<160, 256,0,stream>>>(y2,Wl3,bl3,nullptr,nullptr,(float*)d_out);
}

// Round 12
// 803.009 us; speedup vs baseline: 1.9916x; 1.3079x over previous
//
#include <hip/hip_runtime.h>

#define DEV __device__ __forceinline__

typedef unsigned short u16;
typedef unsigned int   u32;
typedef float f32x4 __attribute__((ext_vector_type(4)));
typedef __bf16 bf16x8 __attribute__((ext_vector_type(8)));

static constexpr float BNS = 0.9999950000374997f; // 1/sqrt(1+1e-5)

DEV float b2f(u32 s){ union{u32 i; float f;} c; c.i = s<<16; return c.f; }
DEV u16   f2b(float x){ union{float f; u32 i;} c; c.f=x; u32 r=c.i + 0x7fffu + ((c.i>>16)&1u); return (u16)(r>>16); }
DEV float leaky(float x){ return x>0.f ? x : 0.2f*x; }
DEV float wredsum(float v){
  #pragma unroll
  for(int d=32; d; d>>=1) v += __shfl_xor(v, d);
  return v;
}
DEV void gl16(const void* g, void* l){
  __builtin_amdgcn_global_load_lds((const __attribute__((address_space(1))) u32*)g,
                                   (__attribute__((address_space(3))) u32*)l, 16, 0, 0);
}
// full bitonic sort, descending, 64 lanes, u32 keys
DEV u32 bsort64u(u32 k, int lane){
  #pragma unroll
  for(int kk=2; kk<=64; kk<<=1){
    #pragma unroll
    for(int j=kk>>1; j>0; j>>=1){
      u32 o = __shfl_xor(k, j);
      bool km = ((lane & kk)==0) == ((lane & j)==0);
      k = (km == (k > o)) ? k : o;
    }
  }
  return k;
}

// ---------- fused prep: x(B,3,N) -> X0(B,N,4) f32 + Xb0(B,N,32 bf16 h,0..) + xx=|h|^2 ----------
__global__ __launch_bounds__(256) void k_prep0(const float* __restrict__ x, float* __restrict__ X0,
                                               u16* __restrict__ Xb0, float* __restrict__ xx){
  int i = blockIdx.x*256 + threadIdx.x;          // b*N+n, 32768
  int b = i>>11, n = i&2047;
  const float* xb = x + ((size_t)b*3)*2048 + n;
  float vx=xb[0], vy=xb[2048], vz=xb[4096];
  f32x4 v; v.x=vx; v.y=vy; v.z=vz; v.w=0.f;
  ((f32x4*)X0)[i] = v;
  u16 h0=f2b(vx),h1=f2b(vy),h2=f2b(vz);
  float hx=b2f(h0), hy=b2f(h1), hz=b2f(h2);
  xx[i] = (hx*hx+hy*hy)+hz*hz;
  ushort4 hh={h0,h1,h2,0};
  ushort4 zz={0,0,0,0};
  u16* p = Xb0 + (size_t)i*32;
  *(ushort4*)(p)=hh;
  #pragma unroll
  for(int c=4;c<32;c+=4) *(ushort4*)(p+c)=zz;
}

// ---------- pack W1 (64,6) f32 -> (64,32) f32 matching padded H1 layout ----------
__global__ __launch_bounds__(256) void k_packw1(const float* __restrict__ W1, float* __restrict__ Wp){
  for(int u=threadIdx.x; u<2048; u+=256){
    int o=u>>5, c=u&31;
    float val=0.f;
    if(c<3)            val = W1[o*6+c];
    else if(c>=4&&c<7) val = W1[o*6+3+(c-4)];
    Wp[u]=val;
  }
}

// ---------- pack all conv weights f32 -> bf16 in one dispatch ----------
__global__ __launch_bounds__(256) void k_w2bAll(const float* __restrict__ W3, const float* __restrict__ W4,
                                                const float* __restrict__ W5, u16* __restrict__ Wb3,
                                                u16* __restrict__ Wb4, u16* __restrict__ Wb5){
  int i = blockIdx.x*256 + threadIdx.x;          // 606208 total
  if(i<16384)       Wb3[i]=f2b(W3[i]);
  else if(i<81920)  Wb4[i-16384]=f2b(W4[i-16384]);
  else if(i<606208) Wb5[i-81920]=f2b(W5[i-81920]);
}

// ---------- xx from Hc bf16 columns (stride 512) ----------
template<int K>
__global__ __launch_bounds__(256) void k_xnorm(const u16* __restrict__ Xc, float* __restrict__ xx){
  const int i = blockIdx.x*256 + threadIdx.x;
  const u16* r = Xc + (size_t)i*512;
  float s=0.f;
  #pragma unroll
  for(int c=0;c<K;c+=8){
    uint4 hv = *(const uint4*)(r+c);
    float h[8];
    h[0]=b2f(hv.x&0xffff); h[1]=b2f(hv.x>>16);
    h[2]=b2f(hv.y&0xffff); h[3]=b2f(hv.y>>16);
    h[4]=b2f(hv.z&0xffff); h[5]=b2f(hv.z>>16);
    h[6]=b2f(hv.w&0xffff); h[7]=b2f(hv.w>>16);
    #pragma unroll
    for(int e=0;e<8;e++) s += h[e]*h[e];
  }
  xx[i]=s;
}

// ---------- layer-1 pd GEMM (BK=32, rows 32-wide), full-S bf16 ----------
__global__ __launch_bounds__(256) void k_pdg32(const u16* __restrict__ Xb, const float* __restrict__ xxg,
                                               u16* __restrict__ Sb){
  __shared__ __align__(16) u16 As[128*32];
  __shared__ __align__(16) u16 Bs[128*32];
  const int tid=threadIdx.x, b=blockIdx.z;
  const int n0=blockIdx.x<<7, o0=blockIdx.y<<7;
  const int wid=tid>>6, lane=tid&63, wr=wid>>1, wc=wid&1, lm=lane&15, quad=lane>>4;
  f32x4 acc[4][4];
  #pragma unroll
  for(int a=0;a<4;a++)
    #pragma unroll
    for(int c=0;c<4;c++) acc[a][c]=(f32x4){0.f,0.f,0.f,0.f};
  const int r0=tid>>2;
  const int kcs=(((tid&3)^((r0>>1)&3))<<3);
  const u16* A0 = Xb + ((size_t)b*2048 + n0 + r0)*32 + kcs;
  const u16* A1 = A0 + (size_t)64*32;
  const u16* B0 = Xb + ((size_t)b*2048 + o0 + r0)*32 + kcs;
  const u16* B1 = B0 + (size_t)64*32;
  u16* Aw = As + wid*512;
  u16* Bw = Bs + wid*512;
  const int qs = ((quad^((lm>>1)&3))<<3);
  __syncthreads();
  gl16(A0, Aw);  gl16(A1, Aw+2048);
  gl16(B0, Bw);  gl16(B1, Bw+2048);
  __syncthreads();
  {
    bf16x8 af[4], bfr[4];
    #pragma unroll
    for(int mi=0;mi<4;mi++) af[mi]=*(const bf16x8*)(As + ((wr<<6)+(mi<<4)+lm)*32 + qs);
    #pragma unroll
    for(int ni=0;ni<4;ni++) bfr[ni]=*(const bf16x8*)(Bs + ((wc<<6)+(ni<<4)+lm)*32 + qs);
    #pragma unroll
    for(int mi=0;mi<4;mi++)
      #pragma unroll
      for(int ni=0;ni<4;ni++)
        acc[mi][ni]=__builtin_amdgcn_mfma_f32_16x16x32_bf16(af[mi],bfr[ni],acc[mi][ni],0,0,0);
  }
  float xn[4];
  #pragma unroll
  for(int ni=0;ni<4;ni++) xn[ni] = xxg[(size_t)b*2048 + o0 + (wc<<6)+(ni<<4)+lm];
  #pragma unroll
  for(int mi=0;mi<4;mi++){
    const int qr = n0 + (wr<<6)+(mi<<4)+(quad<<2);
    #pragma unroll
    for(int ni=0;ni<4;ni++){
      const int cd = o0 + (wc<<6)+(ni<<4)+lm;
      f32x4 cc = acc[mi][ni];
      u16* sp = Sb + ((size_t)b*2048 + qr)*2048 + cd;
      sp[0]   = f2b(cc.x+cc.x-xn[ni]);
      sp[2048]= f2b(cc.y+cc.y-xn[ni]);
      sp[4096]= f2b(cc.z+cc.z-xn[ni]);
      sp[6144]= f2b(cc.w+cc.w-xn[ni]);
    }
  }
}

// ---------- pd GEMM from Hc columns (stride 512), BK=64, full-S bf16 ----------
template<int K>
__global__ __launch_bounds__(256) void k_pdgH(const u16* __restrict__ Xc, const float* __restrict__ xxg,
                                              u16* __restrict__ Sb){
  __shared__ __align__(16) u16 As[128*64];
  __shared__ __align__(16) u16 Bs[128*64];
  const int tid=threadIdx.x, b=blockIdx.z;
  const int n0=blockIdx.x<<7, o0=blockIdx.y<<7;
  const int wid=tid>>6, lane=tid&63, wr=wid>>1, wc=wid&1, lm=lane&15, quad=lane>>4;
  f32x4 acc[4][4];
  #pragma unroll
  for(int a=0;a<4;a++)
    #pragma unroll
    for(int c=0;c<4;c++) acc[a][c]=(f32x4){0.f,0.f,0.f,0.f};
  const int r = tid>>3;                       // 0..31
  const int csw = ((tid&7)^(r&7))<<3;         // swizzled source col within 64
  const u16* A0 = Xc + ((size_t)b*2048 + n0 + r)*512 + csw;
  const u16* B0 = Xc + ((size_t)b*2048 + o0 + r)*512 + csw;
  for(int k0=0;k0<K;k0+=64){
    __syncthreads();
    #pragma unroll
    for(int cc=0;cc<4;cc++){
      gl16(A0+k0+(size_t)(cc*32)*512, As + cc*2048 + wid*512);
      gl16(B0+k0+(size_t)(cc*32)*512, Bs + cc*2048 + wid*512);
    }
    __syncthreads();
    #pragma unroll
    for(int sub=0;sub<2;sub++){
      const int eff = (((sub<<2)|quad)^(lm&7))<<3;
      bf16x8 af[4], bfr[4];
      #pragma unroll
      for(int mi=0;mi<4;mi++) af[mi]=*(const bf16x8*)(As + ((wr<<6)+(mi<<4)+lm)*64 + eff);
      #pragma unroll
      for(int ni=0;ni<4;ni++) bfr[ni]=*(const bf16x8*)(Bs + ((wc<<6)+(ni<<4)+lm)*64 + eff);
      #pragma unroll
      for(int mi=0;mi<4;mi++)
        #pragma unroll
        for(int ni=0;ni<4;ni++)
          acc[mi][ni]=__builtin_amdgcn_mfma_f32_16x16x32_bf16(af[mi],bfr[ni],acc[mi][ni],0,0,0);
    }
  }
  float xn[4];
  #pragma unroll
  for(int ni=0;ni<4;ni++) xn[ni] = xxg[(size_t)b*2048 + o0 + (wc<<6)+(ni<<4)+lm];
  #pragma unroll
  for(int mi=0;mi<4;mi++){
    const int qr = n0 + (wr<<6)+(mi<<4)+(quad<<2);
    #pragma unroll
    for(int ni=0;ni<4;ni++){
      const int cd = o0 + (wc<<6)+(ni<<4)+lm;
      f32x4 cc = acc[mi][ni];
      u16* sp = Sb + ((size_t)b*2048 + qr)*2048 + cd;
      sp[0]   = f2b(cc.x+cc.x-xn[ni]);
      sp[2048]= f2b(cc.y+cc.y-xn[ni]);
      sp[4096]= f2b(cc.z+cc.z-xn[ni]);
      sp[6144]= f2b(cc.w+cc.w-xn[ni]);
    }
  }
}

// ---------- full-row wave-coop top-20 select, u32 keys, kNN-warm-start prime ----------
template<bool L1>
__global__ __launch_bounds__(256) void k_selG(const u16* __restrict__ Sb, int* __restrict__ knn){
  __shared__ u32 buf[4][320];
  __shared__ u32 cw[4];
  const int w=threadIdx.x>>6, lane=threadIdx.x&63;
  const int row = blockIdx.x*4 + w;      // 0..32767
  const int q = row & 2047;
  if(lane==0) cw[w]=0;
  __builtin_amdgcn_wave_barrier();
  __asm__ volatile("s_waitcnt lgkmcnt(0)" ::: "memory");
  const u16* Srow = Sb + (size_t)row*2048;
  int pc;
  if constexpr(L1) pc = (q + 1 + lane) & 2047;
  else             pc = (lane<20) ? knn[(size_t)row*20+lane] : q;
  u32 praw = Srow[pc];
  u32 pmk = praw ^ ((praw&0x8000u)? 0xFFFFu : 0x8000u);
  u32 pkey = (pmk<<16) | (u32)(2047-pc);
  if(lane>=20) pkey=0;
  pkey = bsort64u(pkey,lane);
  u32 top=0;
  u32 T = __shfl(pkey,19);
  u32 Tmk = T>>16;
  auto flush=[&](){
    __builtin_amdgcn_wave_barrier();
    __asm__ volatile("s_waitcnt lgkmcnt(0)" ::: "memory");
    const int cnt=(int)cw[w];
    __builtin_amdgcn_wave_barrier();
    for(int done=0; done<cnt; done+=64){
      u32 bk = (lane < cnt-done) ? buf[w][done+lane] : 0;
      u32 sb = bsort64u(bk, lane);
      u32 rev = __shfl(sb,(31-lane)&63);
      u32 c2 = (lane<32) ? (top>rev?top:rev) : 0;
      #pragma unroll
      for(int j=16;j>0;j>>=1){
        u32 o = __shfl_xor(c2,j);
        bool km=(lane&j)==0;
        c2 = (km==(c2>o))?c2:o;
      }
      top = (lane<20)?c2:0;
    }
    T = __shfl(top,19);
    Tmk = T>>16;
    if(lane==0) cw[w]=0;
    __builtin_amdgcn_wave_barrier();
    __asm__ volatile("s_waitcnt lgkmcnt(0)" ::: "memory");
  };
  #pragma unroll 1
  for(int g=0;g<8;++g){
    const int c0=g*256 + (lane<<2);
    ushort4 s4=*(const ushort4*)(Srow+c0);
    u32 mk0 = (u32)s4.x ^ ((s4.x&0x8000u)?0xFFFFu:0x8000u);
    u32 mk1 = (u32)s4.y ^ ((s4.y&0x8000u)?0xFFFFu:0x8000u);
    u32 mk2 = (u32)s4.z ^ ((s4.z&0x8000u)?0xFFFFu:0x8000u);
    u32 mk3 = (u32)s4.w ^ ((s4.w&0x8000u)?0xFFFFu:0x8000u);
    u32 mmax = max(max(mk0,mk1),max(mk2,mk3));
    if(__ballot(mmax >= Tmk)){
      u32 mks[4]={mk0,mk1,mk2,mk3};
      #pragma unroll
      for(int e=0;e<4;e++){
        const int col=c0+e;
        u32 key=(mks[e]<<16)|(u32)(2047-col);
        if(key>=T && col!=q){
          u32 pos=atomicAdd(&cw[w],1u);
          buf[w][pos]=key;
        }
      }
      __builtin_amdgcn_wave_barrier();
      __asm__ volatile("s_waitcnt lgkmcnt(0)" ::: "memory");
      const int c=(int)cw[w];
      if(c>64) flush();
    }
  }
  flush();
  if(lane<20) knn[(size_t)row*20+lane]=2047-(int)(top&0xFFFFu);
}

// ---------- attention: one-pass online softmax (channel-split, TPP threads/point) ----------
template<int CP,int HS,int TPP>
__global__ __launch_bounds__(256) void k_attn(const float* __restrict__ X, const int* __restrict__ knn,
                                              u16* __restrict__ H){
  constexpr int CH = CP/TPP;
  const int gi = blockIdx.x*256 + threadIdx.x;
  const int i = gi/TPP, t = gi%TPP;
  const float* Xb = X + (((size_t)(i>>11))<<11)*CP;
  const float* q  = X + (size_t)i*CP + t*CH;
  int nb[20];
  { const int* kp = knn + (size_t)i*20;
    #pragma unroll
    for(int j=0;j<20;j++) nb[j]=kp[j]; }
  float qc[CH];
  if constexpr(CH>=4){
    #pragma unroll
    for(int c=0;c<CH;c+=4){
      f32x4 vv = *(const f32x4*)(q+c);
      qc[c]=vv.x; qc[c+1]=vv.y; qc[c+2]=vv.z; qc[c+3]=vv.w;
    }
  } else {
    qc[0]=q[0];
  }
  float m=-3.0e38f, l=0.f;
  float f[CH];
  #pragma unroll
  for(int c=0;c<CH;c++) f[c]=0.f;
  #pragma unroll
  for(int j=0;j<20;j++){
    const float* kr = Xb + (size_t)nb[j]*CP + t*CH;
    float kv[CH];
    float a=0.f;
    if constexpr(CH>=4){
      #pragma unroll
      for(int c=0;c<CH;c+=4){
        f32x4 v = *(const f32x4*)(kr+c);
        kv[c]=v.x; kv[c+1]=v.y; kv[c+2]=v.z; kv[c+3]=v.w;
        a += v.x*qc[c] + v.y*qc[c+1] + v.z*qc[c+2] + v.w*qc[c+3];
      }
    } else {
      kv[0]=kr[0];
      a = qc[0]*kv[0];
    }
    #pragma unroll
    for(int d=1;d<TPP;d<<=1) a += __shfl_xor(a, d);
    float mn = fmaxf(m, a);
    float corr = __expf(m - mn);
    float p = __expf(a - mn);
    l = l*corr + p;
    #pragma unroll
    for(int c=0;c<CH;c++) f[c] = f[c]*corr + p*kv[c];
    m = mn;
  }
  const float inv = 1.f/l;
  #pragma unroll
  for(int c=0;c<CH;c++) f[c]*=inv;
  u16* ho = H + (size_t)i*HS;
  if constexpr(CH>=4){
    #pragma unroll
    for(int c=0;c<CH;c+=4){
      ushort4 qsv = {f2b(qc[c]),f2b(qc[c+1]),f2b(qc[c+2]),f2b(qc[c+3])};
      *(ushort4*)(ho + t*CH + c) = qsv;
      ushort4 fs = {f2b(f[c]-qc[c]),f2b(f[c+1]-qc[c+1]),f2b(f[c+2]-qc[c+2]),f2b(f[c+3]-qc[c+3])};
      *(ushort4*)(ho + CP + t*CH + c) = fs;
    }
  } else {
    ho[t]      = f2b(qc[0]);
    ho[CP+t]   = f2b(f[0]-qc[0]);
  }
  if constexpr(HS > 2*CP){
    ushort4 zz={0,0,0,0};
    *(ushort4*)(ho + 2*CP + t*4) = zz;
    if(t < (HS-2*CP-4*TPP)/4) *(ushort4*)(ho + 2*CP + 4*TPP + t*4) = zz;
  }
}

// ---------- vector conv (O=64) ----------
template<int K>
__global__ __launch_bounds__(256) void k_vconv(const u16* __restrict__ H, const float* __restrict__ Wg,
                                               const float* __restrict__ g, const float* __restrict__ bb,
                                               float* __restrict__ Xout, u16* __restrict__ Hc, int hoff){
  __shared__ __align__(16) float Ws[K*64];   // [k][o]
  for(int u=threadIdx.x; u<K*64; u+=256){
    int o=u&63, kk=u>>6;
    Ws[u]=Wg[o*K+kk];
  }
  __syncthreads();
  const int gi = blockIdx.x*256 + threadIdx.x;
  const int i = gi>>2, oc = gi&3;
  const u16* hr = H + (size_t)i*K;
  float acc[16];
  #pragma unroll
  for(int o=0;o<16;o++) acc[o]=0.f;
  for(int k0=0;k0<K;k0+=8){
    uint4 hv = *(const uint4*)(hr+k0);
    float hh[8];
    hh[0]=b2f(hv.x&0xffff); hh[1]=b2f(hv.x>>16);
    hh[2]=b2f(hv.y&0xffff); hh[3]=b2f(hv.y>>16);
    hh[4]=b2f(hv.z&0xffff); hh[5]=b2f(hv.z>>16);
    hh[6]=b2f(hv.w&0xffff); hh[7]=b2f(hv.w>>16);
    #pragma unroll
    for(int kk=0;kk<8;kk++){
      const f32x4* wr = (const f32x4*)(Ws + (k0+kk)*64 + oc*16);
      #pragma unroll
      for(int o4=0;o4<4;o4++){
        f32x4 w = wr[o4];
        acc[o4*4]  +=hh[kk]*w.x; acc[o4*4+1]+=hh[kk]*w.y;
        acc[o4*4+2]+=hh[kk]*w.z; acc[o4*4+3]+=hh[kk]*w.w;
      }
    }
  }
  const int ob = oc*16;
  #pragma unroll
  for(int o=0;o<16;o++) acc[o]=leaky(acc[o]*(BNS*g[ob+o])+bb[ob+o]);
  float* xo = Xout + (size_t)i*64 + ob;
  #pragma unroll
  for(int o=0;o<16;o+=4){ f32x4 sv={acc[o],acc[o+1],acc[o+2],acc[o+3]}; *(f32x4*)(xo+o)=sv; }
  u16* hc = Hc + (size_t)i*512 + hoff + ob;
  #pragma unroll
  for(int o=0;o<16;o+=4){ ushort4 st={f2b(acc[o]),f2b(acc[o+1]),f2b(acc[o+2]),f2b(acc[o+3])}; *(ushort4*)(hc+o)=st; }
}

// ---------- MFMA conv BK=64 (XOR-swizzled LDS) ----------
template<int K,int OSTR,bool OUT32,int HCS>
__global__ __launch_bounds__(256) void k_cmfma(const u16* __restrict__ Wg, const u16* __restrict__ Hin,
                                               const float* __restrict__ g, const float* __restrict__ bb,
                                               float* __restrict__ Xout, u16* __restrict__ Hc, int hoff){
  __shared__ __align__(16) u16 As[128*64];
  __shared__ __align__(16) u16 Bs[128*64];
  const int tid=threadIdx.x, b=blockIdx.z;
  const int n0=blockIdx.x<<7, o0=blockIdx.y<<7;
  const int wid=tid>>6, lane=tid&63, wr=wid>>1, wc=wid&1, lm=lane&15, quad=lane>>4;
  f32x4 acc[4][4];
  #pragma unroll
  for(int a=0;a<4;a++)
    #pragma unroll
    for(int c=0;c<4;c++) acc[a][c]=(f32x4){0.f,0.f,0.f,0.f};
  const int r = tid>>3;
  const int csw = ((tid&7)^(r&7))<<3;
  const u16* A0 = Wg + (size_t)(o0+r)*K + csw;
  const u16* B0 = Hin + ((size_t)b*2048 + n0 + r)*K + csw;
  for(int k0=0;k0<K;k0+=64){
    __syncthreads();
    #pragma unroll
    for(int cc=0;cc<4;cc++){
      gl16(A0+k0+(size_t)(cc*32)*K, As + cc*2048 + wid*512);
      gl16(B0+k0+(size_t)(cc*32)*K, Bs + cc*2048 + wid*512);
    }
    __syncthreads();
    #pragma unroll
    for(int sub=0;sub<2;sub++){
      const int eff = (((sub<<2)|quad)^(lm&7))<<3;
      bf16x8 af[4], bfr[4];
      #pragma unroll
      for(int mi=0;mi<4;mi++) af[mi]=*(const bf16x8*)(As + ((wr<<6)+(mi<<4)+lm)*64 + eff);
      #pragma unroll
      for(int ni=0;ni<4;ni++) bfr[ni]=*(const bf16x8*)(Bs + ((wc<<6)+(ni<<4)+lm)*64 + eff);
      #pragma unroll
      for(int mi=0;mi<4;mi++)
        #pragma unroll
        for(int ni=0;ni<4;ni++)
          acc[mi][ni]=__builtin_amdgcn_mfma_f32_16x16x32_bf16(af[mi],bfr[ni],acc[mi][ni],0,0,0);
    }
  }
  #pragma unroll
  for(int mi=0;mi<4;mi++){
    const int o = o0 + (wr<<6) + (mi<<4) + (quad<<2);
    float g0=BNS*g[o],  g1v=BNS*g[o+1], g2v=BNS*g[o+2], g3v=BNS*g[o+3];
    float b0=bb[o], b1v=bb[o+1], b2v=bb[o+2], b3v=bb[o+3];
    #pragma unroll
    for(int ni=0;ni<4;ni++){
      const int n = n0 + (wc<<6) + (ni<<4) + lm;
      const size_t pt = (size_t)b*2048 + n;
      f32x4 cc = acc[mi][ni];
      float y0=leaky(cc.x*g0+b0);
      float y1=leaky(cc.y*g1v+b1v);
      float y2=leaky(cc.z*g2v+b2v);
      float y3=leaky(cc.w*g3v+b3v);
      if constexpr(OUT32){
        f32x4 sv={y0,y1,y2,y3};
        *(f32x4*)(Xout + pt*OSTR + o)=sv;
      }
      ushort4 st={f2b(y0),f2b(y1),f2b(y2),f2b(y3)};
      *(ushort4*)(Hc + pt*HCS + hoff + o)=st;
    }
  }
}

// ---------- head: per-point scores = leaky(x5 . Watt^T) ----------
__global__ __launch_bounds__(256) void k_scores(const u16* __restrict__ X5, const float* __restrict__ Watt,
                                                float* __restrict__ S){
  __shared__ __align__(16) f32x4 Wa[1024];
  for(int u=threadIdx.x; u<1024; u+=256){
    f32x4 w; w.x=Watt[u]; w.y=Watt[1024+u]; w.z=Watt[2048+u]; w.w=Watt[3072+u];
    Wa[u]=w;
  }
  __syncthreads();
  const int i = blockIdx.x*256 + threadIdx.x;
  const u16* xr = X5 + (size_t)i*1024;
  f32x4 a={0.f,0.f,0.f,0.f};
  for(int k0=0;k0<1024;k0+=8){
    uint4 hv=*(const uint4*)(xr+k0);
    float hh[8];
    hh[0]=b2f(hv.x&0xffff); hh[1]=b2f(hv.x>>16);
    hh[2]=b2f(hv.y&0xffff); hh[3]=b2f(hv.y>>16);
    hh[4]=b2f(hv.z&0xffff); hh[5]=b2f(hv.z>>16);
    hh[6]=b2f(hv.w&0xffff); hh[7]=b2f(hv.w>>16);
    #pragma unroll
    for(int kk=0;kk<8;kk++){
      f32x4 w=Wa[k0+kk];
      a.x+=hh[kk]*w.x; a.y+=hh[kk]*w.y; a.z+=hh[kk]*w.z; a.w+=hh[kk]*w.w;
    }
  }
  f32x4 sv={leaky(a.x),leaky(a.y),leaky(a.z),leaky(a.w)};
  ((f32x4*)S)[i]=sv;
}

// ---------- head: att[b,h,e] = sum_n x5[b,n,e]*S[b,n,h] (atomic partials) ----------
__global__ __launch_bounds__(256) void k_att(const u16* __restrict__ X5, const float* __restrict__ S,
                                             float* __restrict__ att){
  __shared__ __align__(16) f32x4 Sh[256];
  const int b=blockIdx.z, e=(blockIdx.x<<8)+threadIdx.x, nbase=blockIdx.y<<8;
  Sh[threadIdx.x]=((const f32x4*)S)[(((size_t)b)<<11)+nbase+threadIdx.x];
  __syncthreads();
  f32x4 a={0.f,0.f,0.f,0.f};
  const u16* xp = X5 + ((((size_t)b)<<11)+nbase)*1024 + e;
  for(int nn=0;nn<256;nn++){
    float xv=b2f(xp[(size_t)nn*1024]);
    f32x4 s=Sh[nn];
    a.x+=xv*s.x; a.y+=xv*s.y; a.z+=xv*s.z; a.w+=xv*s.w;
  }
  float* ab = att + (((size_t)b)<<12) + e;
  atomicAdd(ab,      a.x); atomicAdd(ab+1024, a.y);
  atomicAdd(ab+2048, a.z); atomicAdd(ab+3072, a.w);
}

// ---------- head: layernorm + leaky ----------
__global__ __launch_bounds__(256) void k_ln(const float* __restrict__ att, const float* __restrict__ lg,
                                            const float* __restrict__ lb, float* __restrict__ L){
  const int b=blockIdx.x, t=threadIdx.x;
  const float* a = att + (((size_t)b)<<12);
  float s=0.f, sq=0.f;
  for(int u=t;u<4096;u+=256){ float x=a[u]; s+=x; sq+=x*x; }
  s=wredsum(s); sq=wredsum(sq);
  __shared__ float rs[4], rq[4];
  const int wid=t>>6, lane=t&63;
  if(lane==0){ rs[wid]=s; rq[wid]=sq; }
  __syncthreads();
  s=rs[0]+rs[1]+rs[2]+rs[3];
  sq=rq[0]+rq[1]+rq[2]+rq[3];
  const float mean=s*(1.f/4096.f);
  const float var=sq*(1.f/4096.f)-mean*mean;
  const float rstd=rsqrtf(var+1e-5f);
  float* Lb = L + (((size_t)b)<<12);
  for(int u=t;u<4096;u+=256){
    float x=(a[u]-mean)*rstd*lg[u]+lb[u];
    Lb[u]=leaky(x);
  }
}

// ---------- head: fc1 weight-stationary ----------
__global__ __launch_bounds__(256) void k_fcB(const float* __restrict__ Xin, const float* __restrict__ Wg,
                                             const float* __restrict__ bias, const float* __restrict__ g,
                                             const float* __restrict__ bb, float* __restrict__ out){
  const int o = blockIdx.x*4 + (threadIdx.x>>6);   // 512 outputs, 128 blocks
  const int lane = threadIdx.x&63;
  const float* wr = Wg + (size_t)o*4096 + lane*64;
  f32x4 wv[16];
  #pragma unroll
  for(int c=0;c<16;c++) wv[c]=*(const f32x4*)(wr+c*4);
  const float gg=BNS*g[o], bbv=bb[o], bi=bias[o];
  for(int b=0;b<16;b++){
    const float* xr = Xin + (size_t)b*4096 + lane*64;
    float s=0.f;
    #pragma unroll
    for(int c=0;c<16;c++){
      f32x4 xv=*(const f32x4*)(xr+c*4);
      s += xv.x*wv[c].x + xv.y*wv[c].y + xv.z*wv[c].z + xv.w*wv[c].w;
    }
    s = wredsum(s);
    if(lane==0) out[(size_t)b*512+o] = leaky((s+bi)*gg+bbv);
  }
}

// ---------- head: FC (wave-per-output), all-f32 ----------
template<int IN,int OUT,int MODE>
__global__ __launch_bounds__(256) void k_fc(const float* __restrict__ Xin, const float* __restrict__ Wg,
                                            const float* __restrict__ bias, const float* __restrict__ g,
                                            const float* __restrict__ bb, float* __restrict__ out){
  const int gw=(blockIdx.x<<2)+(threadIdx.x>>6);
  const int lane=threadIdx.x&63;
  const int o=gw%OUT, b=gw/OUT;
  constexpr int CHL=IN/64;
  const float* xr = Xin + (size_t)b*IN + lane*CHL;
  const float* wr = Wg  + (size_t)o*IN + lane*CHL;
  float a=0.f;
  #pragma unroll
  for(int c=0;c<CHL;c+=4){
    f32x4 wv=*(const f32x4*)(wr+c);
    f32x4 xv=*(const f32x4*)(xr+c);
    a+=xv.x*wv.x + xv.y*wv.y + xv.z*wv.z + xv.w*wv.w;
  }
  a=wredsum(a);
  if(lane==0){
    float y=a+bias[o];
    if constexpr(MODE<2){
      y=leaky(y*(BNS*g[o])+bb[o]);
    }
    out[(size_t)b*OUT+o]=y;
  }
}

extern "C" void kernel_launch(void* const* d_in, const int* in_sizes, int n_in,
                              void* d_out, int out_size, void* d_ws, size_t ws_size,
                              hipStream_t stream){
  const float* x  =(const float*)d_in[0];
  const float* W1 =(const float*)d_in[1];
  const float* g1 =(const float*)d_in[2];
  const float* b1 =(const float*)d_in[3];
  const float* W2 =(const float*)d_in[4];
  const float* g2 =(const float*)d_in[5];
  const float* b2 =(const float*)d_in[6];
  const float* W3 =(const float*)d_in[7];
  const float* g3 =(const float*)d_in[8];
  const float* b3 =(const float*)d_in[9];
  const float* W4 =(const float*)d_in[10];
  const float* g4 =(const float*)d_in[11];
  const float* b4 =(const float*)d_in[12];
  const float* W5 =(const float*)d_in[13];
  const float* g5 =(const float*)d_in[14];
  const float* b5 =(const float*)d_in[15];
  const float* Watt=(const float*)d_in[16];
  const float* lng=(const float*)d_in[17];
  const float* lnb=(const float*)d_in[18];
  const float* Wl1=(const float*)d_in[19];
  const float* bl1=(const float*)d_in[20];
  const float* g6 =(const float*)d_in[21];
  const float* b6 =(const float*)d_in[22];
  const float* Wl2=(const float*)d_in[23];
  const float* bl2=(const float*)d_in[24];
  const float* g7 =(const float*)d_in[25];
  const float* b7 =(const float*)d_in[26];
  const float* Wl3=(const float*)d_in[27];
  const float* bl3=(const float*)d_in[28];
  char* ws=(char*)d_ws;
  if(ws_size < (size_t)225796096) return;
  float* X0 =(float*)(ws+0);
  u16*   Xb0=(u16*)  (ws+524288);
  float* X1 =(float*)(ws+2621440);
  float* X2 =(float*)(ws+11010048);
  float* X3 =(float*)(ws+19398656);
  u16*   H  =(u16*)  (ws+36175872);
  u16*   Hc =(u16*)  (ws+52953088);
  u16*   S  =(u16*)  (ws+86507520);     // (16,2048,2048) bf16 = 128 MB
  u16*   X5 =(u16*)  (ws+86507520);     // overlays S (dead by conv5), 64 MB
  float* xx =(float*)(ws+220725248);
  int*   knn=(int*)  (ws+220856320);
  float* Wp1=(float*)(ws+223477760);
  u16*   Wb3=(u16*)  (ws+223485952);
  u16*   Wb4=(u16*)  (ws+223518720);
  u16*   Wb5=(u16*)  (ws+223649792);
  float* Ssc=(float*)(ws+224698368);
  float* att=(float*)(ws+225222656);
  float* L  =(float*)(ws+225484800);
  float* y1 =(float*)(ws+225746944);
  float* y2 =(float*)(ws+225779712);

  k_prep0 <<<128,256,0,stream>>>(x,X0,Xb0,xx);
  k_packw1<<<1,  256,0,stream>>>(W1,Wp1);
  k_w2bAll<<<2368,256,0,stream>>>(W3,W4,W5,Wb3,Wb4,Wb5);

  // ---- layer 1 (C=3, bf16-quantized kNN) ----
  k_pdg32<<<dim3(16,16,16),256,0,stream>>>(Xb0,xx,S);
  k_selG<true><<<8192,256,0,stream>>>(S,knn);
  k_attn<4,32,4><<<512,256,0,stream>>>(X0,knn,H);
  k_vconv<32>   <<<512,256,0,stream>>>(H,Wp1,g1,b1,X1,Hc,0);

  // ---- layer 2 (C=64, from Hc[0:64]) ----
  k_xnorm<64><<<128,256,0,stream>>>(Hc,xx);
  k_pdgH<64> <<<dim3(16,16,16),256,0,stream>>>(Hc,xx,S);
  k_selG<false><<<8192,256,0,stream>>>(S,knn);
  k_attn<64,128,4><<<512,256,0,stream>>>(X1,knn,H);
  k_vconv<128>    <<<512,256,0,stream>>>(H,W2,g2,b2,X2,Hc,64);

  // ---- layer 3 (C=64, from Hc[64:128]) ----
  k_xnorm<64><<<128,256,0,stream>>>(Hc+64,xx);
  k_pdgH<64> <<<dim3(16,16,16),256,0,stream>>>(Hc+64,xx,S);
  k_selG<false><<<8192,256,0,stream>>>(S,knn);
  k_attn<64,128,4><<<512,256,0,stream>>>(X2,knn,H);
  k_cmfma<128,128,true,512><<<dim3(16,1,16),256,0,stream>>>(Wb3,H,g3,b3,X3,Hc,128);

  // ---- layer 4 (C=128, from Hc[128:256]) ----
  k_xnorm<128><<<128,256,0,stream>>>(Hc+128,xx);
  k_pdgH<128> <<<dim3(16,16,16),256,0,stream>>>(Hc+128,xx,S);
  k_selG<false><<<8192,256,0,stream>>>(S,knn);
  k_attn<128,256,8><<<1024,256,0,stream>>>(X3,knn,H);
  k_cmfma<256,1,false,512><<<dim3(16,2,16),256,0,stream>>>(Wb4,H,g4,b4,nullptr,Hc,256);

  // ---- conv5 (512 -> 1024) ----
  k_cmfma<512,1,false,1024><<<dim3(16,8,16),256,0,stream>>>(Wb5,Hc,g5,b5,nullptr,X5,0);

  // ---- head ----
  k_scores<<<128,256,0,stream>>>(X5,Watt,Ssc);
  hipMemsetAsync(att,0,16*4096*4,stream);
  k_att   <<<dim3(4,8,16),256,0,stream>>>(X5,Ssc,att);
  k_ln    <<<16,256,0,stream>>>(att,lng,lnb,L);
  k_fcB   <<<128,256,0,stream>>>(L,Wl1,bl1,g6,b6,y1);
  k_fc<512,256,0> <<<1024,256,0,stream>>>(y1,Wl2,bl2,g7,b7,y2);
  k_fc<256,40,2>  <<<160, 256,0,stream>>>(y2,Wl3,bl3,nullptr,nullptr,(float*)d_out);
}